// Round 1
// baseline (2698.260 us; speedup 1.0000x reference)
//
#include <hip/hip_runtime.h>
#include <math.h>

#define B_  4
#define L_  2048
#define H_  1024
#define NH_ 16
#define DK_ 64

// ---------------------------------------------------------------------------
// Projection GEMM: y[n,o] = sum_h x[n,h] * W[o,h] + b[o], scattered to
// (B, NH, L, DK) layout. 64x64 tile, BK=16, 256 threads, 4x4 microtile.
// blockIdx.z selects {Wq, Wk, Wv}.
// ---------------------------------------------------------------------------
__global__ __launch_bounds__(256) void proj_kernel(
    const float* __restrict__ x,
    const float* __restrict__ Wq, const float* __restrict__ Wk, const float* __restrict__ Wv,
    const float* __restrict__ bq, const float* __restrict__ bk, const float* __restrict__ bv,
    float* __restrict__ qo, float* __restrict__ ko, float* __restrict__ vo)
{
    const int z = blockIdx.z;
    const float* W  = (z == 0) ? Wq : (z == 1) ? Wk : Wv;
    const float* bs = (z == 0) ? bq : (z == 1) ? bk : bv;
    float* dst      = (z == 0) ? qo : (z == 1) ? ko : vo;

    const int n0 = blockIdx.y * 64;   // row tile (n = b*L + l)
    const int o0 = blockIdx.x * 64;   // col tile
    const int h  = blockIdx.x;        // head index (64 cols per head, tile==head)

    __shared__ float Xs[16][68];      // [k][n] transposed, padded
    __shared__ float Ws[16][68];      // [k][o] transposed, padded

    const int t   = threadIdx.x;
    const int tx  = t & 15, ty = t >> 4;
    const int lr  = t >> 2;           // load row 0..63
    const int lc4 = (t & 3) << 2;     // load col (float4 base) 0..12

    float acc[4][4] = {};

    for (int k0 = 0; k0 < H_; k0 += 16) {
        float4 xv = *(const float4*)(x + (size_t)(n0 + lr) * H_ + k0 + lc4);
        float4 wv = *(const float4*)(W + (size_t)(o0 + lr) * H_ + k0 + lc4);
        __syncthreads();
        Xs[lc4+0][lr] = xv.x; Xs[lc4+1][lr] = xv.y; Xs[lc4+2][lr] = xv.z; Xs[lc4+3][lr] = xv.w;
        Ws[lc4+0][lr] = wv.x; Ws[lc4+1][lr] = wv.y; Ws[lc4+2][lr] = wv.z; Ws[lc4+3][lr] = wv.w;
        __syncthreads();
        #pragma unroll
        for (int kk = 0; kk < 16; ++kk) {
            float4 a  = *(const float4*)&Xs[kk][ty << 2];
            float4 bb = *(const float4*)&Ws[kk][tx << 2];
            float av[4] = {a.x, a.y, a.z, a.w};
            float bv4[4] = {bb.x, bb.y, bb.z, bb.w};
            #pragma unroll
            for (int i = 0; i < 4; ++i)
                #pragma unroll
                for (int j = 0; j < 4; ++j)
                    acc[i][j] += av[i] * bv4[j];
        }
    }

    #pragma unroll
    for (int i = 0; i < 4; ++i) {
        const int n = n0 + (ty << 2) + i;
        const int bb = n >> 11;             // n / L_
        const int l  = n & (L_ - 1);
        float4 r;
        r.x = acc[i][0] + bs[o0 + (tx << 2) + 0];
        r.y = acc[i][1] + bs[o0 + (tx << 2) + 1];
        r.z = acc[i][2] + bs[o0 + (tx << 2) + 2];
        r.w = acc[i][3] + bs[o0 + (tx << 2) + 3];
        *(float4*)(dst + (((size_t)(bb * NH_ + h) * L_ + l) << 6) + (tx << 2)) = r;
    }
}

// ---------------------------------------------------------------------------
// Attention: one block per (b, h, 64-query tile). Two passes over K tiles:
//   pass 1: exact row max m and denom l (online softmax, no O)
//   pass 2: exact probs, O += P*V (registers), colsum atomics, ctx_sum atomics
// LDS: Qt/KP/Vs transposed 64x68; KP reused for K^T then P^T (<64KB total).
// ---------------------------------------------------------------------------
__global__ __launch_bounds__(256) void attn_kernel(
    const float* __restrict__ qg, const float* __restrict__ kg, const float* __restrict__ vg,
    float* __restrict__ ctx_sum, float* __restrict__ colsum)
{
    const int qt = blockIdx.x & 31;
    const int bh = blockIdx.x >> 5;
    const int b  = bh >> 4;
    const int h  = bh & 15;

    const float* Q = qg + ((size_t)bh * L_ + qt * 64) * DK_;
    const float* K = kg + (size_t)bh * L_ * DK_;
    const float* V = vg + (size_t)bh * L_ * DK_;

    __shared__ float Qt[64][68];   // [d][q-row]
    __shared__ float KP[64][68];   // [d][k-col] during S ; [k-col][q-row] during PV
    __shared__ float Vs[64][68];   // [k-row][d]
    __shared__ float m_s[64], il_s[64];
    __shared__ float red[16][68];

    const int t  = threadIdx.x;
    const int tx = t & 15, ty = t >> 4;

    // load Q transposed
    #pragma unroll
    for (int i = 0; i < 4; ++i) {
        int idx = t + i * 256;
        int r = idx >> 4, c4 = (idx & 15) << 2;
        float4 v = *(const float4*)(Q + r * DK_ + c4);
        Qt[c4+0][r] = v.x; Qt[c4+1][r] = v.y; Qt[c4+2][r] = v.z; Qt[c4+3][r] = v.w;
    }

    float m[4], l[4];
    #pragma unroll
    for (int i = 0; i < 4; ++i) { m[i] = -INFINITY; l[i] = 0.f; }

    // ---------------- pass 1 ----------------
    for (int kt = 0; kt < 32; ++kt) {
        const float* Kg = K + kt * 64 * DK_;
        float4 kv[4];
        #pragma unroll
        for (int i = 0; i < 4; ++i) {
            int idx = t + i * 256;
            kv[i] = *(const float4*)(Kg + (idx >> 4) * DK_ + ((idx & 15) << 2));
        }
        __syncthreads();
        #pragma unroll
        for (int i = 0; i < 4; ++i) {
            int idx = t + i * 256;
            int r = idx >> 4, c4 = (idx & 15) << 2;
            KP[c4+0][r] = kv[i].x; KP[c4+1][r] = kv[i].y; KP[c4+2][r] = kv[i].z; KP[c4+3][r] = kv[i].w;
        }
        __syncthreads();

        float s[4][4] = {};
        #pragma unroll 8
        for (int d = 0; d < 64; ++d) {
            float4 a  = *(const float4*)&Qt[d][ty << 2];
            float4 bb = *(const float4*)&KP[d][tx << 2];
            float av[4] = {a.x, a.y, a.z, a.w};
            float bv4[4] = {bb.x, bb.y, bb.z, bb.w};
            #pragma unroll
            for (int i = 0; i < 4; ++i)
                #pragma unroll
                for (int j = 0; j < 4; ++j)
                    s[i][j] += av[i] * bv4[j];
        }
        #pragma unroll
        for (int i = 0; i < 4; ++i) {
            #pragma unroll
            for (int j = 0; j < 4; ++j) s[i][j] *= 0.125f;
            float smax = fmaxf(fmaxf(s[i][0], s[i][1]), fmaxf(s[i][2], s[i][3]));
            float mn = fmaxf(m[i], smax);
            float add = __expf(s[i][0] - mn) + __expf(s[i][1] - mn)
                      + __expf(s[i][2] - mn) + __expf(s[i][3] - mn);
            l[i] = l[i] * __expf(m[i] - mn) + add;
            m[i] = mn;
        }
    }

    // reduce (m,l) across the 16 tx lanes sharing each row group
    #pragma unroll
    for (int off = 1; off < 16; off <<= 1) {
        #pragma unroll
        for (int i = 0; i < 4; ++i) {
            float mo = __shfl_xor(m[i], off);
            float lo = __shfl_xor(l[i], off);
            float mn = fmaxf(m[i], mo);
            l[i] = l[i] * __expf(m[i] - mn) + lo * __expf(mo - mn);
            m[i] = mn;
        }
    }
    if (tx == 0) {
        #pragma unroll
        for (int i = 0; i < 4; ++i) {
            m_s[(ty << 2) + i]  = m[i];
            il_s[(ty << 2) + i] = 1.0f / l[i];
        }
    }

    float o_acc[4][4] = {};

    // ---------------- pass 2 ----------------
    for (int kt = 0; kt < 32; ++kt) {
        const float* Kg = K + kt * 64 * DK_;
        const float* Vg = V + kt * 64 * DK_;
        float4 kv[4], vv[4];
        #pragma unroll
        for (int i = 0; i < 4; ++i) {
            int idx = t + i * 256;
            kv[i] = *(const float4*)(Kg + (idx >> 4) * DK_ + ((idx & 15) << 2));
            vv[i] = *(const float4*)(Vg + (idx >> 4) * DK_ + ((idx & 15) << 2));
        }
        __syncthreads();
        #pragma unroll
        for (int i = 0; i < 4; ++i) {
            int idx = t + i * 256;
            int r = idx >> 4, c4 = (idx & 15) << 2;
            KP[c4+0][r] = kv[i].x; KP[c4+1][r] = kv[i].y; KP[c4+2][r] = kv[i].z; KP[c4+3][r] = kv[i].w;
            *(float4*)&Vs[r][c4] = vv[i];
        }
        __syncthreads();

        float s[4][4] = {};
        #pragma unroll 8
        for (int d = 0; d < 64; ++d) {
            float4 a  = *(const float4*)&Qt[d][ty << 2];
            float4 bb = *(const float4*)&KP[d][tx << 2];
            float av[4] = {a.x, a.y, a.z, a.w};
            float bv4[4] = {bb.x, bb.y, bb.z, bb.w};
            #pragma unroll
            for (int i = 0; i < 4; ++i)
                #pragma unroll
                for (int j = 0; j < 4; ++j)
                    s[i][j] += av[i] * bv4[j];
        }
        __syncthreads();   // done reading K^T; reuse KP for P^T

        float mloc[4], illoc[4];
        #pragma unroll
        for (int i = 0; i < 4; ++i) {
            mloc[i]  = m_s[(ty << 2) + i];
            illoc[i] = il_s[(ty << 2) + i];
        }
        #pragma unroll
        for (int i = 0; i < 4; ++i)
            #pragma unroll
            for (int j = 0; j < 4; ++j) {
                float p = __expf(s[i][j] * 0.125f - mloc[i]) * illoc[i];
                KP[(tx << 2) + j][(ty << 2) + i] = p;   // P^T: [k][q]
            }
        __syncthreads();

        // column (key) sums over this block's 64 query rows
        {
            int c = t & 63, qtr = t >> 6;
            float ps = 0.f;
            #pragma unroll
            for (int rr = 0; rr < 16; ++rr) ps += KP[c][qtr * 16 + rr];
            red[qtr][c] = ps;
        }
        __syncthreads();
        if (t < 64) {
            float tot = red[0][t] + red[1][t] + red[2][t] + red[3][t];
            atomicAdd(&colsum[(size_t)b * L_ + kt * 64 + t], tot);
        }

        // O += P * V
        #pragma unroll 8
        for (int kk = 0; kk < 64; ++kk) {
            float4 a  = *(const float4*)&KP[kk][ty << 2];   // P^T[k][q rows]
            float4 vv4 = *(const float4*)&Vs[kk][tx << 2];  // V[k][d]
            float av[4] = {a.x, a.y, a.z, a.w};
            float bv4[4] = {vv4.x, vv4.y, vv4.z, vv4.w};
            #pragma unroll
            for (int i = 0; i < 4; ++i)
                #pragma unroll
                for (int j = 0; j < 4; ++j)
                    o_acc[i][j] += av[i] * bv4[j];
        }
    }

    // context column sums (over this block's 64 query rows) -> ctx_sum
    __syncthreads();
    #pragma unroll
    for (int j = 0; j < 4; ++j) {
        float ssum = o_acc[0][j] + o_acc[1][j] + o_acc[2][j] + o_acc[3][j];
        red[ty][(tx << 2) + j] = ssum;
    }
    __syncthreads();
    if (t < 64) {
        float tot = 0.f;
        #pragma unroll
        for (int r = 0; r < 16; ++r) tot += red[r][t];
        atomicAdd(&ctx_sum[(size_t)b * H_ + h * DK_ + t], tot);
    }
}

// ---------------------------------------------------------------------------
// pooled[b,o] = bo[o] + sum_h (ctx_sum[b,h]/L) * Wo[o,h]
// ---------------------------------------------------------------------------
__global__ __launch_bounds__(256) void pooled_kernel(
    const float* __restrict__ ctx_sum, const float* __restrict__ Wo,
    const float* __restrict__ bo, float* __restrict__ out)
{
    const int b = blockIdx.x;
    __shared__ float cm[H_];
    for (int i = threadIdx.x; i < H_; i += 256)
        cm[i] = ctx_sum[b * H_ + i] * (1.0f / (float)L_);
    __syncthreads();
    for (int o = threadIdx.x; o < H_; o += 256) {
        const float4* w4 = (const float4*)(Wo + (size_t)o * H_);
        float acc = 0.f;
        for (int h4 = 0; h4 < H_ / 4; ++h4) {
            float4 wv = w4[h4];
            acc += cm[h4*4+0]*wv.x + cm[h4*4+1]*wv.y + cm[h4*4+2]*wv.z + cm[h4*4+3]*wv.w;
        }
        out[b * H_ + o] = acc + bo[o];
    }
}

__global__ void weights_kernel(const float* __restrict__ colsum, float* __restrict__ out)
{
    int i = blockIdx.x * 256 + threadIdx.x;
    if (i < B_ * L_)
        out[B_ * H_ + i] = colsum[i] * (1.0f / (float)(NH_ * L_));
}

// ---------------------------------------------------------------------------
extern "C" void kernel_launch(void* const* d_in, const int* in_sizes, int n_in,
                              void* d_out, int out_size, void* d_ws, size_t ws_size,
                              hipStream_t stream)
{
    const float* x  = (const float*)d_in[0];
    const float* Wq = (const float*)d_in[1];
    const float* bq = (const float*)d_in[2];
    const float* Wk = (const float*)d_in[3];
    const float* bk = (const float*)d_in[4];
    const float* Wv = (const float*)d_in[5];
    const float* bv = (const float*)d_in[6];
    const float* Wo = (const float*)d_in[7];
    const float* bo = (const float*)d_in[8];
    float* out = (float*)d_out;

    float* ws      = (float*)d_ws;
    float* ctx_sum = ws;                                   // B*H   = 4096
    float* colsum  = ws + (B_ * H_);                       // B*L   = 8192
    float* qw      = ws + (B_ * H_) + (B_ * L_);
    const size_t qkv_elems = (size_t)B_ * NH_ * L_ * DK_;  // 8388608
    float* kw = qw + qkv_elems;
    float* vw = kw + qkv_elems;

    hipMemsetAsync(ws, 0, (B_ * H_ + B_ * L_) * sizeof(float), stream);

    dim3 pgrid(H_ / 64, (B_ * L_) / 64, 3);
    proj_kernel<<<pgrid, 256, 0, stream>>>(x, Wq, Wk, Wv, bq, bk, bv, qw, kw, vw);

    attn_kernel<<<B_ * NH_ * (L_ / 64), 256, 0, stream>>>(qw, kw, vw, ctx_sum, colsum);

    pooled_kernel<<<B_, 256, 0, stream>>>(ctx_sum, Wo, bo, out);
    weights_kernel<<<(B_ * L_) / 256, 256, 0, stream>>>(colsum, out);
}

// Round 4
// 644.013 us; speedup vs baseline: 4.1898x; 4.1898x over previous
//
#include <hip/hip_runtime.h>
#include <math.h>

#define B_  4
#define L_  2048
#define H_  1024
#define NH_ 16
#define DK_ 64

typedef unsigned short ushort_t;
typedef __attribute__((ext_vector_type(8))) short short8;
typedef __attribute__((ext_vector_type(4))) float f32x4;

__device__ __forceinline__ ushort_t f2b(float f) {   // RNE fp32->bf16
    unsigned int u = __float_as_uint(f);
    return (ushort_t)((u + 0x7FFFu + ((u >> 16) & 1u)) >> 16);
}
__device__ __forceinline__ float b2f(ushort_t h) {
    return __uint_as_float(((unsigned int)h) << 16);
}

__device__ __forceinline__ void gload_lds16(const void* g, void* l) {
    __builtin_amdgcn_global_load_lds((const __attribute__((address_space(1))) void*)g,
                                     (__attribute__((address_space(3))) void*)l, 16, 0, 0);
}

// trunc-split 8 fp32 -> (hi, lo) bf16 frags; h+l represents f to ~2^-16 rel.
__device__ __forceinline__ void split8(const float4& a, const float4& b,
                                       short8& h, short8& l) {
    float f[8] = {a.x, a.y, a.z, a.w, b.x, b.y, b.z, b.w};
    #pragma unroll
    for (int e = 0; e < 8; ++e) {
        unsigned int u  = __float_as_uint(f[e]);
        float fh = __uint_as_float(u & 0xFFFF0000u);
        float r  = f[e] - fh;
        h[e] = (short)(u >> 16);
        l[e] = (short)(__float_as_uint(r) >> 16);
    }
}

// ---------------------------------------------------------------------------
// RNE split cast for weights: src fp32 -> (hi, lo) bf16 planes
// ---------------------------------------------------------------------------
__global__ __launch_bounds__(256) void wsplit_kernel(const float* __restrict__ src,
                                                     ushort_t* __restrict__ ph,
                                                     ushort_t* __restrict__ pl, int n4)
{
    int i = blockIdx.x * 256 + threadIdx.x;
    if (i < n4) {
        float4 v = ((const float4*)src)[i];
        ushort4 h, l;
        float f[4] = {v.x, v.y, v.z, v.w};
        ushort_t hh[4], ll[4];
        #pragma unroll
        for (int e = 0; e < 4; ++e) {
            hh[e] = f2b(f[e]);
            ll[e] = f2b(f[e] - b2f(hh[e]));
        }
        h.x = hh[0]; h.y = hh[1]; h.z = hh[2]; h.w = hh[3];
        l.x = ll[0]; l.y = ll[1]; l.z = ll[2]; l.w = ll[3];
        ((ushort4*)ph)[i] = h;
        ((ushort4*)pl)[i] = l;
    }
}

// ---------------------------------------------------------------------------
// Q/K projection, split-bf16 3-term MFMA. 128x128 tile, BK=32, 256 threads.
// x staged fp32 (8 chunks/row, swizzle c^(row&7)), trunc-split to frags in-reg.
// W staged from pre-split bf16 planes (4 chunks/row, swizzle c^((row>>1)&3)).
// Output: q,k as RNE-split (hi,lo) bf16 planes, (B,NH,L,DK) layout.
// ---------------------------------------------------------------------------
__global__ __launch_bounds__(256) void proj_split(
    const float* __restrict__ x,
    const ushort_t* __restrict__ Wqh, const ushort_t* __restrict__ Wql,
    const ushort_t* __restrict__ Wkh, const ushort_t* __restrict__ Wkl,
    const float* __restrict__ bq, const float* __restrict__ bk,
    ushort_t* __restrict__ qh, ushort_t* __restrict__ ql,
    ushort_t* __restrict__ kh, ushort_t* __restrict__ kl)
{
    const int z = blockIdx.z;
    const ushort_t* Wh = z ? Wkh : Wqh;
    const ushort_t* Wl = z ? Wkl : Wql;
    const float* bias  = z ? bk  : bq;
    ushort_t* dh       = z ? kh  : qh;
    ushort_t* dl       = z ? kl  : ql;

    const int n0 = blockIdx.y * 128;
    const int o0 = blockIdx.x * 128;

    __shared__ float    Asf[128 * 32];   // fp32 x tile
    __shared__ ushort_t Bsh[128 * 32];   // W hi
    __shared__ ushort_t Bsl[128 * 32];   // W lo

    const int t = threadIdx.x;
    const int lane = t & 63, w = t >> 6;
    const int ln = lane & 15, qd = lane >> 4;
    const int wy = w >> 1, wx = w & 1;

    // x staging: 4 rounds; slot = i*256+t; 8 chunks(4 floats)/row
    int rxS[4], cxS[4];
    #pragma unroll
    for (int i = 0; i < 4; ++i) {
        int slot = i * 256 + t;
        rxS[i] = slot >> 3;
        cxS[i] = (slot & 7) ^ (rxS[i] & 7);
    }
    // W staging: 2 rounds; 4 chunks(8 ushorts)/row
    int rwS[2], cwS[2];
    #pragma unroll
    for (int i = 0; i < 2; ++i) {
        int slot = i * 256 + t;
        rwS[i] = slot >> 2;
        cwS[i] = (slot & 3) ^ ((rwS[i] >> 1) & 3);
    }

    f32x4 acc[4][4];
    #pragma unroll
    for (int i = 0; i < 4; ++i)
        #pragma unroll
        for (int j = 0; j < 4; ++j) acc[i][j] = (f32x4){0.f, 0.f, 0.f, 0.f};

    for (int k0 = 0; k0 < H_; k0 += 32) {
        __syncthreads();
        #pragma unroll
        for (int i = 0; i < 4; ++i)
            gload_lds16(x + (size_t)(n0 + rxS[i]) * H_ + k0 + cxS[i] * 4,
                        &Asf[i * 1024 + (t & ~63) * 4]);
        #pragma unroll
        for (int i = 0; i < 2; ++i) {
            gload_lds16(Wh + (size_t)(o0 + rwS[i]) * H_ + k0 + cwS[i] * 8,
                        &Bsh[i * 2048 + (t & ~63) * 8]);
            gload_lds16(Wl + (size_t)(o0 + rwS[i]) * H_ + k0 + cwS[i] * 8,
                        &Bsl[i * 2048 + (t & ~63) * 8]);
        }
        __syncthreads();

        short8 bh4[4], bl4[4];
        #pragma unroll
        for (int nt = 0; nt < 4; ++nt) {
            int row = wx * 64 + nt * 16 + ln;
            int sz = (qd ^ ((row >> 1) & 3)) << 3;
            bh4[nt] = *(const short8*)&Bsh[row * 32 + sz];
            bl4[nt] = *(const short8*)&Bsl[row * 32 + sz];
        }
        #pragma unroll
        for (int mt = 0; mt < 4; ++mt) {
            int row = wy * 64 + mt * 16 + ln;
            int r7 = row & 7;
            float4 fa = *(const float4*)&Asf[row * 32 + (((2 * qd)     ^ r7) << 2)];
            float4 fb = *(const float4*)&Asf[row * 32 + (((2 * qd + 1) ^ r7) << 2)];
            short8 ah, al;
            split8(fa, fb, ah, al);
            #pragma unroll
            for (int nt = 0; nt < 4; ++nt) {
                acc[mt][nt] = __builtin_amdgcn_mfma_f32_16x16x32_bf16(al, bh4[nt], acc[mt][nt], 0, 0, 0);
                acc[mt][nt] = __builtin_amdgcn_mfma_f32_16x16x32_bf16(ah, bl4[nt], acc[mt][nt], 0, 0, 0);
                acc[mt][nt] = __builtin_amdgcn_mfma_f32_16x16x32_bf16(ah, bh4[nt], acc[mt][nt], 0, 0, 0);
            }
        }
    }

    // epilogue: C row=(lane>>4)*4+reg (token), col=lane&15 (o); RNE split store
    #pragma unroll
    for (int nt = 0; nt < 4; ++nt) {
        int o = o0 + wx * 64 + nt * 16 + ln;
        float bvv = bias[o];
        int hh = o >> 6, d = o & 63;
        #pragma unroll
        for (int mt = 0; mt < 4; ++mt) {
            #pragma unroll
            for (int r = 0; r < 4; ++r) {
                int n = n0 + wy * 64 + mt * 16 + qd * 4 + r;
                int bb = n >> 11, l = n & (L_ - 1);
                float val = acc[mt][nt][r] + bvv;
                ushort_t vh = f2b(val);
                ushort_t vl = f2b(val - b2f(vh));
                size_t idx = (((size_t)(bb * NH_ + hh) * L_ + l) << 6) + d;
                dh[idx] = vh;
                dl[idx] = vl;
            }
        }
    }
}

// ---------------------------------------------------------------------------
// Attention column sums cs[b,h,k] = sum_q P[q,k], split-bf16 6-MFMA scores.
// m == 0 softmax (scores bounded ~|3|): pass1 accumulates l = sum exp(s),
// pass2 emits normalized probs -> per-key column sums -> atomics.
// ---------------------------------------------------------------------------
__global__ __launch_bounds__(256) void attn_split(
    const ushort_t* __restrict__ qh, const ushort_t* __restrict__ ql,
    const ushort_t* __restrict__ kh, const ushort_t* __restrict__ kl,
    float* __restrict__ cs)
{
    const int qt = blockIdx.x & 31;
    const int bh = blockIdx.x >> 5;

    const int t = threadIdx.x;
    const int lane = t & 63, w = t >> 6;
    const int ln = lane & 15, qd = lane >> 4;

    __shared__ ushort_t Ksh[64 * 64];
    __shared__ ushort_t Ksl[64 * 64];
    __shared__ float cs_all[4][64];

    const size_t headoff = (size_t)bh * L_ * DK_;
    const size_t qoff = headoff + ((size_t)(qt * 64 + w * 16 + ln)) * DK_;
    const short8 aq0h = *(const short8*)(qh + qoff + qd * 8);
    const short8 aq1h = *(const short8*)(qh + qoff + 32 + qd * 8);
    const short8 aq0l = *(const short8*)(ql + qoff + qd * 8);
    const short8 aq1l = *(const short8*)(ql + qoff + 32 + qd * 8);

    int rowS[2], cS[2];
    #pragma unroll
    for (int i = 0; i < 2; ++i) {
        int slot = i * 256 + t;
        rowS[i] = slot >> 3;
        cS[i] = (slot & 7) ^ (rowS[i] & 7);
    }

    const float SC = 0.125f;   // 1/sqrt(DK)
    float l_run[4] = {0.f, 0.f, 0.f, 0.f};

    // ---------------- pass 1: l = sum_k exp(s) ----------------
    for (int kt = 0; kt < 32; ++kt) {
        __syncthreads();
        #pragma unroll
        for (int i = 0; i < 2; ++i) {
            gload_lds16(kh + headoff + ((size_t)(kt * 64 + rowS[i]) << 6) + cS[i] * 8,
                        &Ksh[i * 2048 + (t & ~63) * 8]);
            gload_lds16(kl + headoff + ((size_t)(kt * 64 + rowS[i]) << 6) + cS[i] * 8,
                        &Ksl[i * 2048 + (t & ~63) * 8]);
        }
        __syncthreads();

        #pragma unroll
        for (int nt = 0; nt < 4; ++nt) {
            int kr = nt * 16 + ln;
            int sz0 = ((qd     ^ (kr & 7)) << 3);
            int sz1 = (((qd + 4) ^ (kr & 7)) << 3);
            short8 b0h = *(const short8*)&Ksh[kr * 64 + sz0];
            short8 b1h = *(const short8*)&Ksh[kr * 64 + sz1];
            short8 b0l = *(const short8*)&Ksl[kr * 64 + sz0];
            short8 b1l = *(const short8*)&Ksl[kr * 64 + sz1];
            f32x4 zz = (f32x4){0.f, 0.f, 0.f, 0.f};
            zz = __builtin_amdgcn_mfma_f32_16x16x32_bf16(aq0l, b0h, zz, 0, 0, 0);
            zz = __builtin_amdgcn_mfma_f32_16x16x32_bf16(aq1l, b1h, zz, 0, 0, 0);
            zz = __builtin_amdgcn_mfma_f32_16x16x32_bf16(aq0h, b0l, zz, 0, 0, 0);
            zz = __builtin_amdgcn_mfma_f32_16x16x32_bf16(aq1h, b1l, zz, 0, 0, 0);
            zz = __builtin_amdgcn_mfma_f32_16x16x32_bf16(aq0h, b0h, zz, 0, 0, 0);
            zz = __builtin_amdgcn_mfma_f32_16x16x32_bf16(aq1h, b1h, zz, 0, 0, 0);
            #pragma unroll
            for (int r = 0; r < 4; ++r)
                l_run[r] += __expf(zz[r] * SC);
        }
    }

    // combine l across the 16 lanes (cols) sharing each row quartet
    #pragma unroll
    for (int off = 1; off < 16; off <<= 1)
        #pragma unroll
        for (int r = 0; r < 4; ++r)
            l_run[r] += __shfl_xor(l_run[r], off);
    float inv_l[4];
    #pragma unroll
    for (int r = 0; r < 4; ++r) inv_l[r] = 1.0f / l_run[r];

    // ---------------- pass 2: column sums ----------------
    for (int kt = 0; kt < 32; ++kt) {
        __syncthreads();
        #pragma unroll
        for (int i = 0; i < 2; ++i) {
            gload_lds16(kh + headoff + ((size_t)(kt * 64 + rowS[i]) << 6) + cS[i] * 8,
                        &Ksh[i * 2048 + (t & ~63) * 8]);
            gload_lds16(kl + headoff + ((size_t)(kt * 64 + rowS[i]) << 6) + cS[i] * 8,
                        &Ksl[i * 2048 + (t & ~63) * 8]);
        }
        __syncthreads();

        float colp[4];
        #pragma unroll
        for (int nt = 0; nt < 4; ++nt) {
            int kr = nt * 16 + ln;
            int sz0 = ((qd     ^ (kr & 7)) << 3);
            int sz1 = (((qd + 4) ^ (kr & 7)) << 3);
            short8 b0h = *(const short8*)&Ksh[kr * 64 + sz0];
            short8 b1h = *(const short8*)&Ksh[kr * 64 + sz1];
            short8 b0l = *(const short8*)&Ksl[kr * 64 + sz0];
            short8 b1l = *(const short8*)&Ksl[kr * 64 + sz1];
            f32x4 zz = (f32x4){0.f, 0.f, 0.f, 0.f};
            zz = __builtin_amdgcn_mfma_f32_16x16x32_bf16(aq0l, b0h, zz, 0, 0, 0);
            zz = __builtin_amdgcn_mfma_f32_16x16x32_bf16(aq1l, b1h, zz, 0, 0, 0);
            zz = __builtin_amdgcn_mfma_f32_16x16x32_bf16(aq0h, b0l, zz, 0, 0, 0);
            zz = __builtin_amdgcn_mfma_f32_16x16x32_bf16(aq1h, b1l, zz, 0, 0, 0);
            zz = __builtin_amdgcn_mfma_f32_16x16x32_bf16(aq0h, b0h, zz, 0, 0, 0);
            zz = __builtin_amdgcn_mfma_f32_16x16x32_bf16(aq1h, b1h, zz, 0, 0, 0);
            colp[nt] = __expf(zz[0] * SC) * inv_l[0] + __expf(zz[1] * SC) * inv_l[1]
                     + __expf(zz[2] * SC) * inv_l[2] + __expf(zz[3] * SC) * inv_l[3];
        }
        #pragma unroll
        for (int nt = 0; nt < 4; ++nt) {
            colp[nt] += __shfl_xor(colp[nt], 16);
            colp[nt] += __shfl_xor(colp[nt], 32);
        }
        float mine = (qd == 0) ? colp[0] : (qd == 1) ? colp[1] : (qd == 2) ? colp[2] : colp[3];
        cs_all[w][lane] = mine;
        __syncthreads();
        if (t < 64) {
            float tot = cs_all[0][t] + cs_all[1][t] + cs_all[2][t] + cs_all[3][t];
            atomicAdd(&cs[(size_t)bh * L_ + kt * 64 + t], tot);
        }
    }
}

// ---------------------------------------------------------------------------
// T[b,h,h'] = sum_l cs[b,h,l] * x[b,l,h']   (fp32, atomic over l-splits)
// ---------------------------------------------------------------------------
__global__ __launch_bounds__(256) void ctx1_kernel(
    const float* __restrict__ cs, const float* __restrict__ x, float* __restrict__ T)
{
    const int o0 = blockIdx.x * 64, b = blockIdx.y, l0 = blockIdx.z * 512;
    const int t = threadIdx.x, o = t & 63, hg = t >> 6;
    __shared__ float cs_s[16][128];
    float acc[4] = {};

    for (int ch = 0; ch < 4; ++ch) {
        int lbase = l0 + ch * 128;
        __syncthreads();
        for (int i = t; i < 2048; i += 256) {
            int h = i >> 7, lc = i & 127;
            cs_s[h][lc] = cs[((size_t)(b * NH_ + h) << 11) + lbase + lc];
        }
        __syncthreads();
        for (int lc = 0; lc < 128; ++lc) {
            float xv = x[((size_t)(b * L_ + lbase + lc) << 10) + o0 + o];
            #pragma unroll
            for (int j = 0; j < 4; ++j) acc[j] += cs_s[hg * 4 + j][lc] * xv;
        }
    }
    #pragma unroll
    for (int j = 0; j < 4; ++j)
        atomicAdd(&T[((size_t)(b * NH_ + hg * 4 + j) << 10) + o0 + o], acc[j]);
}

// ---------------------------------------------------------------------------
// ctx[b,o] = sum_h' T[b, o>>6, h'] * Wv[o,h'] + L*bv[o]
// ---------------------------------------------------------------------------
__global__ __launch_bounds__(256) void ctx2_kernel(
    const float* __restrict__ T, const float* __restrict__ Wv,
    const float* __restrict__ bv, float* __restrict__ ctx)
{
    const int b = blockIdx.y;
    const int o = blockIdx.x * 256 + threadIdx.x;
    const int hh = o >> 6;
    const float4* wr = (const float4*)(Wv + (size_t)o * H_);
    const float4* tr = (const float4*)(T + ((size_t)(b * NH_ + hh) << 10));
    float acc = (float)L_ * bv[o];
    for (int i = 0; i < H_ / 4; ++i) {
        float4 wv = wr[i], tv = tr[i];
        acc += wv.x * tv.x + wv.y * tv.y + wv.z * tv.z + wv.w * tv.w;
    }
    ctx[(b << 10) + o] = acc;
}

// ---------------------------------------------------------------------------
// pooled[b,o] = bo[o] + sum_h (ctx[b,h]/L) * Wo[o,h]
// ---------------------------------------------------------------------------
__global__ __launch_bounds__(256) void pooled_kernel(
    const float* __restrict__ ctx, const float* __restrict__ Wo,
    const float* __restrict__ bo, float* __restrict__ out)
{
    const int b = blockIdx.x;
    __shared__ float cm[H_];
    for (int i = threadIdx.x; i < H_; i += 256)
        cm[i] = ctx[b * H_ + i] * (1.0f / (float)L_);
    __syncthreads();
    for (int o = threadIdx.x; o < H_; o += 256) {
        const float4* w4 = (const float4*)(Wo + (size_t)o * H_);
        float acc = 0.f;
        for (int h4 = 0; h4 < H_ / 4; ++h4) {
            float4 wv = w4[h4];
            acc += cm[h4 * 4 + 0] * wv.x + cm[h4 * 4 + 1] * wv.y
                 + cm[h4 * 4 + 2] * wv.z + cm[h4 * 4 + 3] * wv.w;
        }
        out[b * H_ + o] = acc + bo[o];
    }
}

__global__ void weights_kernel(const float* __restrict__ cs, float* __restrict__ out)
{
    int i = blockIdx.x * 256 + threadIdx.x;   // 8192
    int b = i >> 11, k = i & (L_ - 1);
    float s = 0.f;
    #pragma unroll
    for (int h = 0; h < NH_; ++h) s += cs[((size_t)(b * NH_ + h) << 11) + k];
    out[B_ * H_ + i] = s * (1.0f / (float)(NH_ * L_));
}

// ---------------------------------------------------------------------------
extern "C" void kernel_launch(void* const* d_in, const int* in_sizes, int n_in,
                              void* d_out, int out_size, void* d_ws, size_t ws_size,
                              hipStream_t stream)
{
    const float* x  = (const float*)d_in[0];
    const float* Wq = (const float*)d_in[1];
    const float* bq = (const float*)d_in[2];
    const float* Wk = (const float*)d_in[3];
    const float* bk = (const float*)d_in[4];
    const float* Wv = (const float*)d_in[5];
    const float* bv = (const float*)d_in[6];
    const float* Wo = (const float*)d_in[7];
    const float* bo = (const float*)d_in[8];
    float* out = (float*)d_out;

    float* ws  = (float*)d_ws;
    float* cs  = ws;                       // B*NH*L = 131072 f
    float* T   = ws + 131072;              // B*NH*H =  65536 f
    float* ctx = ws + 196608;              // B*H    =   4096 f
    ushort_t* base = (ushort_t*)(ws + 200704);
    const size_t QE = 8388608;             // B*NH*L*DK
    ushort_t* qhb = base;
    ushort_t* qlb = base + QE;
    ushort_t* khb = base + 2 * QE;
    ushort_t* klb = base + 3 * QE;
    ushort_t* wqh = base + 4 * QE;
    ushort_t* wql = wqh + 1048576;
    ushort_t* wkh = wql + 1048576;
    ushort_t* wkl = wkh + 1048576;

    hipMemsetAsync(ws, 0, (131072 + 65536) * sizeof(float), stream);

    wsplit_kernel<<<1024, 256, 0, stream>>>(Wq, wqh, wql, 262144);
    wsplit_kernel<<<1024, 256, 0, stream>>>(Wk, wkh, wkl, 262144);

    proj_split<<<dim3(8, 64, 2), 256, 0, stream>>>(x, wqh, wql, wkh, wkl, bq, bk,
                                                   qhb, qlb, khb, klb);

    attn_split<<<B_ * NH_ * (L_ / 64), 256, 0, stream>>>(qhb, qlb, khb, klb, cs);

    ctx1_kernel<<<dim3(16, 4, 4), 256, 0, stream>>>(cs, x, T);
    ctx2_kernel<<<dim3(4, 4), 256, 0, stream>>>(T, Wv, bv, ctx);
    pooled_kernel<<<B_, 256, 0, stream>>>(ctx, Wo, bo, out);
    weights_kernel<<<(B_ * L_) / 256, 256, 0, stream>>>(cs, out);
}

// Round 5
// 482.990 us; speedup vs baseline: 5.5866x; 1.3334x over previous
//
#include <hip/hip_runtime.h>
#include <math.h>

#define B_  4
#define L_  2048
#define H_  1024
#define NH_ 16
#define DK_ 64

// 0.125 * log2(e): folded into q so attn can use exp2 directly
#define QSC 0.18033688011112043f

typedef unsigned short ushort_t;
typedef __attribute__((ext_vector_type(8))) short short8;
typedef __attribute__((ext_vector_type(4))) float f32x4;

__device__ __forceinline__ ushort_t f2b(float f) {   // RNE fp32->bf16
    unsigned int u = __float_as_uint(f);
    return (ushort_t)((u + 0x7FFFu + ((u >> 16) & 1u)) >> 16);
}
__device__ __forceinline__ float b2f(ushort_t h) {
    return __uint_as_float(((unsigned int)h) << 16);
}

__device__ __forceinline__ void gload_lds16(const void* g, void* l) {
    __builtin_amdgcn_global_load_lds((const __attribute__((address_space(1))) void*)g,
                                     (__attribute__((address_space(3))) void*)l, 16, 0, 0);
}

// trunc-split 8 fp32 -> (hi, lo) bf16 frags
__device__ __forceinline__ void split8(const float4& a, const float4& b,
                                       short8& h, short8& l) {
    float f[8] = {a.x, a.y, a.z, a.w, b.x, b.y, b.z, b.w};
    #pragma unroll
    for (int e = 0; e < 8; ++e) {
        unsigned int u  = __float_as_uint(f[e]);
        float fh = __uint_as_float(u & 0xFFFF0000u);
        float r  = f[e] - fh;
        h[e] = (short)(u >> 16);
        l[e] = (short)(__float_as_uint(r) >> 16);
    }
}

// ---------------------------------------------------------------------------
// RNE split cast for weights: src fp32 -> (hi, lo) bf16 planes
// ---------------------------------------------------------------------------
__global__ __launch_bounds__(256) void wsplit_kernel(const float* __restrict__ src,
                                                     ushort_t* __restrict__ ph,
                                                     ushort_t* __restrict__ pl, int n4)
{
    int i = blockIdx.x * 256 + threadIdx.x;
    if (i < n4) {
        float4 v = ((const float4*)src)[i];
        ushort4 h, l;
        float f[4] = {v.x, v.y, v.z, v.w};
        ushort_t hh[4], ll[4];
        #pragma unroll
        for (int e = 0; e < 4; ++e) {
            hh[e] = f2b(f[e]);
            ll[e] = f2b(f[e] - b2f(hh[e]));
        }
        h.x = hh[0]; h.y = hh[1]; h.z = hh[2]; h.w = hh[3];
        l.x = ll[0]; l.y = ll[1]; l.z = ll[2]; l.w = ll[3];
        ((ushort4*)ph)[i] = h;
        ((ushort4*)pl)[i] = l;
    }
}

// ---------------------------------------------------------------------------
// Q/K projection, split-bf16 3-term MFMA. 128x128 tile, BK=32, 256 threads.
// q outputs prescaled by QSC so attention scores are already in log2 units.
// ---------------------------------------------------------------------------
__global__ __launch_bounds__(256) void proj_split(
    const float* __restrict__ x,
    const ushort_t* __restrict__ Wqh, const ushort_t* __restrict__ Wql,
    const ushort_t* __restrict__ Wkh, const ushort_t* __restrict__ Wkl,
    const float* __restrict__ bq, const float* __restrict__ bk,
    ushort_t* __restrict__ qh, ushort_t* __restrict__ ql,
    ushort_t* __restrict__ kh, ushort_t* __restrict__ kl)
{
    const int z = blockIdx.z;
    const ushort_t* Wh = z ? Wkh : Wqh;
    const ushort_t* Wl = z ? Wkl : Wql;
    const float* bias  = z ? bk  : bq;
    ushort_t* dh       = z ? kh  : qh;
    ushort_t* dl       = z ? kl  : ql;
    const float qs     = z ? 1.0f : QSC;

    const int n0 = blockIdx.y * 128;
    const int o0 = blockIdx.x * 128;

    __shared__ float    Asf[128 * 32];   // fp32 x tile
    __shared__ ushort_t Bsh[128 * 32];   // W hi
    __shared__ ushort_t Bsl[128 * 32];   // W lo

    const int t = threadIdx.x;
    const int lane = t & 63, w = t >> 6;
    const int ln = lane & 15, qd = lane >> 4;
    const int wy = w >> 1, wx = w & 1;

    int rxS[4], cxS[4];
    #pragma unroll
    for (int i = 0; i < 4; ++i) {
        int slot = i * 256 + t;
        rxS[i] = slot >> 3;
        cxS[i] = (slot & 7) ^ (rxS[i] & 7);
    }
    int rwS[2], cwS[2];
    #pragma unroll
    for (int i = 0; i < 2; ++i) {
        int slot = i * 256 + t;
        rwS[i] = slot >> 2;
        cwS[i] = (slot & 3) ^ ((rwS[i] >> 1) & 3);
    }

    f32x4 acc[4][4];
    #pragma unroll
    for (int i = 0; i < 4; ++i)
        #pragma unroll
        for (int j = 0; j < 4; ++j) acc[i][j] = (f32x4){0.f, 0.f, 0.f, 0.f};

    for (int k0 = 0; k0 < H_; k0 += 32) {
        __syncthreads();
        #pragma unroll
        for (int i = 0; i < 4; ++i)
            gload_lds16(x + (size_t)(n0 + rxS[i]) * H_ + k0 + cxS[i] * 4,
                        &Asf[i * 1024 + (t & ~63) * 4]);
        #pragma unroll
        for (int i = 0; i < 2; ++i) {
            gload_lds16(Wh + (size_t)(o0 + rwS[i]) * H_ + k0 + cwS[i] * 8,
                        &Bsh[i * 2048 + (t & ~63) * 8]);
            gload_lds16(Wl + (size_t)(o0 + rwS[i]) * H_ + k0 + cwS[i] * 8,
                        &Bsl[i * 2048 + (t & ~63) * 8]);
        }
        __syncthreads();

        short8 bh4[4], bl4[4];
        #pragma unroll
        for (int nt = 0; nt < 4; ++nt) {
            int row = wx * 64 + nt * 16 + ln;
            int sz = (qd ^ ((row >> 1) & 3)) << 3;
            bh4[nt] = *(const short8*)&Bsh[row * 32 + sz];
            bl4[nt] = *(const short8*)&Bsl[row * 32 + sz];
        }
        #pragma unroll
        for (int mt = 0; mt < 4; ++mt) {
            int row = wy * 64 + mt * 16 + ln;
            int r7 = row & 7;
            float4 fa = *(const float4*)&Asf[row * 32 + (((2 * qd)     ^ r7) << 2)];
            float4 fb = *(const float4*)&Asf[row * 32 + (((2 * qd + 1) ^ r7) << 2)];
            short8 ah, al;
            split8(fa, fb, ah, al);
            #pragma unroll
            for (int nt = 0; nt < 4; ++nt) {
                acc[mt][nt] = __builtin_amdgcn_mfma_f32_16x16x32_bf16(al, bh4[nt], acc[mt][nt], 0, 0, 0);
                acc[mt][nt] = __builtin_amdgcn_mfma_f32_16x16x32_bf16(ah, bl4[nt], acc[mt][nt], 0, 0, 0);
                acc[mt][nt] = __builtin_amdgcn_mfma_f32_16x16x32_bf16(ah, bh4[nt], acc[mt][nt], 0, 0, 0);
            }
        }
    }

    #pragma unroll
    for (int nt = 0; nt < 4; ++nt) {
        int o = o0 + wx * 64 + nt * 16 + ln;
        float bvv = bias[o];
        int hh = o >> 6, d = o & 63;
        #pragma unroll
        for (int mt = 0; mt < 4; ++mt) {
            #pragma unroll
            for (int r = 0; r < 4; ++r) {
                int n = n0 + wy * 64 + mt * 16 + qd * 4 + r;
                int bb = n >> 11, l = n & (L_ - 1);
                float val = (acc[mt][nt][r] + bvv) * qs;
                ushort_t vh = f2b(val);
                ushort_t vl = f2b(val - b2f(vh));
                size_t idx = (((size_t)(bb * NH_ + hh) * L_ + l) << 6) + d;
                dh[idx] = vh;
                dl[idx] = vl;
            }
        }
    }
}

// ---------------------------------------------------------------------------
// Attention column sums cs[b,h,k] = sum_q P[q,k], split-bf16 6-MFMA scores.
// q prescaled by 0.125*log2(e) -> probs = exp2(zz)/l, no per-element scaling.
// ---------------------------------------------------------------------------
__global__ __launch_bounds__(256) void attn_split(
    const ushort_t* __restrict__ qh, const ushort_t* __restrict__ ql,
    const ushort_t* __restrict__ kh, const ushort_t* __restrict__ kl,
    float* __restrict__ cs)
{
    const int qt = blockIdx.x & 31;
    const int bh = blockIdx.x >> 5;

    const int t = threadIdx.x;
    const int lane = t & 63, w = t >> 6;
    const int ln = lane & 15, qd = lane >> 4;

    __shared__ ushort_t Ksh[64 * 64];
    __shared__ ushort_t Ksl[64 * 64];
    __shared__ float cs_all[4][64];

    const size_t headoff = (size_t)bh * L_ * DK_;
    const size_t qoff = headoff + ((size_t)(qt * 64 + w * 16 + ln)) * DK_;
    const short8 aq0h = *(const short8*)(qh + qoff + qd * 8);
    const short8 aq1h = *(const short8*)(qh + qoff + 32 + qd * 8);
    const short8 aq0l = *(const short8*)(ql + qoff + qd * 8);
    const short8 aq1l = *(const short8*)(ql + qoff + 32 + qd * 8);

    int rowS[2], cS[2];
    #pragma unroll
    for (int i = 0; i < 2; ++i) {
        int slot = i * 256 + t;
        rowS[i] = slot >> 3;
        cS[i] = (slot & 7) ^ (rowS[i] & 7);
    }

    float l_run[4] = {0.f, 0.f, 0.f, 0.f};

    // ---------------- pass 1: l = sum_k exp2(zz) ----------------
    for (int kt = 0; kt < 32; ++kt) {
        __syncthreads();
        #pragma unroll
        for (int i = 0; i < 2; ++i) {
            gload_lds16(kh + headoff + ((size_t)(kt * 64 + rowS[i]) << 6) + cS[i] * 8,
                        &Ksh[i * 2048 + (t & ~63) * 8]);
            gload_lds16(kl + headoff + ((size_t)(kt * 64 + rowS[i]) << 6) + cS[i] * 8,
                        &Ksl[i * 2048 + (t & ~63) * 8]);
        }
        __syncthreads();

        #pragma unroll
        for (int nt = 0; nt < 4; ++nt) {
            int kr = nt * 16 + ln;
            int sz0 = ((qd     ^ (kr & 7)) << 3);
            int sz1 = (((qd + 4) ^ (kr & 7)) << 3);
            short8 b0h = *(const short8*)&Ksh[kr * 64 + sz0];
            short8 b1h = *(const short8*)&Ksh[kr * 64 + sz1];
            short8 b0l = *(const short8*)&Ksl[kr * 64 + sz0];
            short8 b1l = *(const short8*)&Ksl[kr * 64 + sz1];
            f32x4 zz = (f32x4){0.f, 0.f, 0.f, 0.f};
            zz = __builtin_amdgcn_mfma_f32_16x16x32_bf16(aq0l, b0h, zz, 0, 0, 0);
            zz = __builtin_amdgcn_mfma_f32_16x16x32_bf16(aq1l, b1h, zz, 0, 0, 0);
            zz = __builtin_amdgcn_mfma_f32_16x16x32_bf16(aq0h, b0l, zz, 0, 0, 0);
            zz = __builtin_amdgcn_mfma_f32_16x16x32_bf16(aq1h, b1l, zz, 0, 0, 0);
            zz = __builtin_amdgcn_mfma_f32_16x16x32_bf16(aq0h, b0h, zz, 0, 0, 0);
            zz = __builtin_amdgcn_mfma_f32_16x16x32_bf16(aq1h, b1h, zz, 0, 0, 0);
            #pragma unroll
            for (int r = 0; r < 4; ++r)
                l_run[r] += exp2f(zz[r]);
        }
    }

    #pragma unroll
    for (int off = 1; off < 16; off <<= 1)
        #pragma unroll
        for (int r = 0; r < 4; ++r)
            l_run[r] += __shfl_xor(l_run[r], off);
    float inv_l[4];
    #pragma unroll
    for (int r = 0; r < 4; ++r) inv_l[r] = 1.0f / l_run[r];

    // ---------------- pass 2: column sums ----------------
    for (int kt = 0; kt < 32; ++kt) {
        __syncthreads();
        #pragma unroll
        for (int i = 0; i < 2; ++i) {
            gload_lds16(kh + headoff + ((size_t)(kt * 64 + rowS[i]) << 6) + cS[i] * 8,
                        &Ksh[i * 2048 + (t & ~63) * 8]);
            gload_lds16(kl + headoff + ((size_t)(kt * 64 + rowS[i]) << 6) + cS[i] * 8,
                        &Ksl[i * 2048 + (t & ~63) * 8]);
        }
        __syncthreads();

        float colp[4];
        #pragma unroll
        for (int nt = 0; nt < 4; ++nt) {
            int kr = nt * 16 + ln;
            int sz0 = ((qd     ^ (kr & 7)) << 3);
            int sz1 = (((qd + 4) ^ (kr & 7)) << 3);
            short8 b0h = *(const short8*)&Ksh[kr * 64 + sz0];
            short8 b1h = *(const short8*)&Ksh[kr * 64 + sz1];
            short8 b0l = *(const short8*)&Ksl[kr * 64 + sz0];
            short8 b1l = *(const short8*)&Ksl[kr * 64 + sz1];
            f32x4 zz = (f32x4){0.f, 0.f, 0.f, 0.f};
            zz = __builtin_amdgcn_mfma_f32_16x16x32_bf16(aq0l, b0h, zz, 0, 0, 0);
            zz = __builtin_amdgcn_mfma_f32_16x16x32_bf16(aq1l, b1h, zz, 0, 0, 0);
            zz = __builtin_amdgcn_mfma_f32_16x16x32_bf16(aq0h, b0l, zz, 0, 0, 0);
            zz = __builtin_amdgcn_mfma_f32_16x16x32_bf16(aq1h, b1l, zz, 0, 0, 0);
            zz = __builtin_amdgcn_mfma_f32_16x16x32_bf16(aq0h, b0h, zz, 0, 0, 0);
            zz = __builtin_amdgcn_mfma_f32_16x16x32_bf16(aq1h, b1h, zz, 0, 0, 0);
            colp[nt] = exp2f(zz[0]) * inv_l[0] + exp2f(zz[1]) * inv_l[1]
                     + exp2f(zz[2]) * inv_l[2] + exp2f(zz[3]) * inv_l[3];
        }
        #pragma unroll
        for (int nt = 0; nt < 4; ++nt) {
            colp[nt] += __shfl_xor(colp[nt], 16);
            colp[nt] += __shfl_xor(colp[nt], 32);
        }
        float mine = (qd == 0) ? colp[0] : (qd == 1) ? colp[1] : (qd == 2) ? colp[2] : colp[3];
        cs_all[w][lane] = mine;
        __syncthreads();
        if (t < 64) {
            float tot = cs_all[0][t] + cs_all[1][t] + cs_all[2][t] + cs_all[3][t];
            atomicAdd(&cs[(size_t)bh * L_ + kt * 64 + t], tot);
        }
    }
}

// ---------------------------------------------------------------------------
// T[b,h,h'] = sum_l cs[b,h,l] * x[b,l,h']   (fp32, atomic over 8 l-splits)
// ---------------------------------------------------------------------------
__global__ __launch_bounds__(256) void ctx1_kernel(
    const float* __restrict__ cs, const float* __restrict__ x, float* __restrict__ T)
{
    const int o0 = blockIdx.x * 64, b = blockIdx.y, l0 = blockIdx.z * 256;
    const int t = threadIdx.x, o = t & 63, hg = t >> 6;
    __shared__ float cs_s[16][128];
    float acc[4] = {};

    for (int ch = 0; ch < 2; ++ch) {
        int lbase = l0 + ch * 128;
        __syncthreads();
        for (int i = t; i < 2048; i += 256) {
            int h = i >> 7, lc = i & 127;
            cs_s[h][lc] = cs[((size_t)(b * NH_ + h) << 11) + lbase + lc];
        }
        __syncthreads();
        for (int lc = 0; lc < 128; ++lc) {
            float xv = x[((size_t)(b * L_ + lbase + lc) << 10) + o0 + o];
            #pragma unroll
            for (int j = 0; j < 4; ++j) acc[j] += cs_s[hg * 4 + j][lc] * xv;
        }
    }
    #pragma unroll
    for (int j = 0; j < 4; ++j)
        atomicAdd(&T[((size_t)(b * NH_ + hg * 4 + j) << 10) + o0 + o], acc[j]);
}

// ---------------------------------------------------------------------------
// ctx[b,o] = sum_h' T[b, o>>6, h'] * Wv[o,h'] + L*bv[o]
// one wave per output row; coalesced float4 row reads + shuffle reduce
// ---------------------------------------------------------------------------
__global__ __launch_bounds__(256) void ctx2_kernel(
    const float* __restrict__ T, const float* __restrict__ Wv,
    const float* __restrict__ bv, float* __restrict__ ctx)
{
    const int gid  = blockIdx.x * 4 + (threadIdx.x >> 6);   // 0..4095
    const int lane = threadIdx.x & 63;
    const int b = gid >> 10, o = gid & (H_ - 1);
    const float4* wr = (const float4*)(Wv + (size_t)o * H_);
    const float4* tr = (const float4*)(T + ((size_t)(b * NH_ + (o >> 6)) << 10));
    float acc = 0.f;
    #pragma unroll
    for (int i = 0; i < 4; ++i) {
        float4 wv = wr[lane + i * 64];
        float4 tv = tr[lane + i * 64];
        acc += wv.x * tv.x + wv.y * tv.y + wv.z * tv.z + wv.w * tv.w;
    }
    #pragma unroll
    for (int off = 32; off; off >>= 1) acc += __shfl_xor(acc, off);
    if (lane == 0) ctx[(b << 10) + o] = acc + (float)L_ * bv[o];
}

// ---------------------------------------------------------------------------
// pooled[b,o] = bo[o] + (1/L) * sum_h ctx[b,h] * Wo[o,h]
// one wave per output row
// ---------------------------------------------------------------------------
__global__ __launch_bounds__(256) void pooled_kernel(
    const float* __restrict__ ctx, const float* __restrict__ Wo,
    const float* __restrict__ bo, float* __restrict__ out)
{
    const int gid  = blockIdx.x * 4 + (threadIdx.x >> 6);   // 0..4095
    const int lane = threadIdx.x & 63;
    const int b = gid >> 10, o = gid & (H_ - 1);
    const float4* wr = (const float4*)(Wo + (size_t)o * H_);
    const float4* cr = (const float4*)(ctx + ((size_t)b << 10));
    float acc = 0.f;
    #pragma unroll
    for (int i = 0; i < 4; ++i) {
        float4 wv = wr[lane + i * 64];
        float4 cv = cr[lane + i * 64];
        acc += wv.x * cv.x + wv.y * cv.y + wv.z * cv.z + wv.w * cv.w;
    }
    #pragma unroll
    for (int off = 32; off; off >>= 1) acc += __shfl_xor(acc, off);
    if (lane == 0) out[(b << 10) + o] = acc * (1.0f / (float)L_) + bo[o];
}

__global__ void weights_kernel(const float* __restrict__ cs, float* __restrict__ out)
{
    int i = blockIdx.x * 256 + threadIdx.x;   // 8192
    int b = i >> 11, k = i & (L_ - 1);
    float s = 0.f;
    #pragma unroll
    for (int h = 0; h < NH_; ++h) s += cs[((size_t)(b * NH_ + h) << 11) + k];
    out[B_ * H_ + i] = s * (1.0f / (float)(NH_ * L_));
}

// ---------------------------------------------------------------------------
extern "C" void kernel_launch(void* const* d_in, const int* in_sizes, int n_in,
                              void* d_out, int out_size, void* d_ws, size_t ws_size,
                              hipStream_t stream)
{
    const float* x  = (const float*)d_in[0];
    const float* Wq = (const float*)d_in[1];
    const float* bq = (const float*)d_in[2];
    const float* Wk = (const float*)d_in[3];
    const float* bk = (const float*)d_in[4];
    const float* Wv = (const float*)d_in[5];
    const float* bv = (const float*)d_in[6];
    const float* Wo = (const float*)d_in[7];
    const float* bo = (const float*)d_in[8];
    float* out = (float*)d_out;

    float* ws  = (float*)d_ws;
    float* cs  = ws;                       // B*NH*L = 131072 f
    float* T   = ws + 131072;              // B*NH*H =  65536 f
    float* ctx = ws + 196608;              // B*H    =   4096 f
    ushort_t* base = (ushort_t*)(ws + 200704);
    const size_t QE = 8388608;             // B*NH*L*DK
    ushort_t* qhb = base;
    ushort_t* qlb = base + QE;
    ushort_t* khb = base + 2 * QE;
    ushort_t* klb = base + 3 * QE;
    ushort_t* wqh = base + 4 * QE;
    ushort_t* wql = wqh + 1048576;
    ushort_t* wkh = wql + 1048576;
    ushort_t* wkl = wkh + 1048576;

    hipMemsetAsync(ws, 0, (131072 + 65536) * sizeof(float), stream);

    wsplit_kernel<<<1024, 256, 0, stream>>>(Wq, wqh, wql, 262144);
    wsplit_kernel<<<1024, 256, 0, stream>>>(Wk, wkh, wkl, 262144);

    proj_split<<<dim3(8, 64, 2), 256, 0, stream>>>(x, wqh, wql, wkh, wkl, bq, bk,
                                                   qhb, qlb, khb, klb);

    attn_split<<<B_ * NH_ * (L_ / 64), 256, 0, stream>>>(qhb, qlb, khb, klb, cs);

    ctx1_kernel<<<dim3(16, 4, 8), 256, 0, stream>>>(cs, x, T);
    ctx2_kernel<<<1024, 256, 0, stream>>>(T, Wv, bv, ctx);
    pooled_kernel<<<1024, 256, 0, stream>>>(ctx, Wo, bo, out);
    weights_kernel<<<(B_ * L_) / 256, 256, 0, stream>>>(cs, out);
}

// Round 6
// 431.209 us; speedup vs baseline: 6.2574x; 1.1201x over previous
//
#include <hip/hip_runtime.h>
#include <math.h>

#define B_  4
#define L_  2048
#define H_  1024
#define NH_ 16
#define DK_ 64

// 0.125 * log2(e): folded into q so attn scores are already in log2 units
#define QSC 0.18033688011112043f

typedef unsigned short ushort_t;
typedef __attribute__((ext_vector_type(8))) short short8;
typedef __attribute__((ext_vector_type(4))) float f32x4;

__device__ __forceinline__ ushort_t f2b(float f) {   // RNE fp32->bf16
    unsigned int u = __float_as_uint(f);
    return (ushort_t)((u + 0x7FFFu + ((u >> 16) & 1u)) >> 16);
}
__device__ __forceinline__ float b2f(ushort_t h) {
    return __uint_as_float(((unsigned int)h) << 16);
}
// raw v_exp_f32 (2^x), no libm range fixup
__device__ __forceinline__ float fexp2(float x) {
    return __builtin_amdgcn_exp2f(x);
}

__device__ __forceinline__ void gload_lds16(const void* g, void* l) {
    __builtin_amdgcn_global_load_lds((const __attribute__((address_space(1))) void*)g,
                                     (__attribute__((address_space(3))) void*)l, 16, 0, 0);
}

// trunc-split 8 fp32 -> (hi, lo) bf16 frags
__device__ __forceinline__ void split8(const float4& a, const float4& b,
                                       short8& h, short8& l) {
    float f[8] = {a.x, a.y, a.z, a.w, b.x, b.y, b.z, b.w};
    #pragma unroll
    for (int e = 0; e < 8; ++e) {
        unsigned int u  = __float_as_uint(f[e]);
        float fh = __uint_as_float(u & 0xFFFF0000u);
        float r  = f[e] - fh;
        h[e] = (short)(u >> 16);
        l[e] = (short)(__float_as_uint(r) >> 16);
    }
}

// ---------------------------------------------------------------------------
// RNE split cast for weights: src fp32 -> (hi, lo) bf16 planes
// ---------------------------------------------------------------------------
__global__ __launch_bounds__(256) void wsplit_kernel(const float* __restrict__ src,
                                                     ushort_t* __restrict__ ph,
                                                     ushort_t* __restrict__ pl, int n4)
{
    int i = blockIdx.x * 256 + threadIdx.x;
    if (i < n4) {
        float4 v = ((const float4*)src)[i];
        ushort4 h, l;
        float f[4] = {v.x, v.y, v.z, v.w};
        ushort_t hh[4], ll[4];
        #pragma unroll
        for (int e = 0; e < 4; ++e) {
            hh[e] = f2b(f[e]);
            ll[e] = f2b(f[e] - b2f(hh[e]));
        }
        h.x = hh[0]; h.y = hh[1]; h.z = hh[2]; h.w = hh[3];
        l.x = ll[0]; l.y = ll[1]; l.z = ll[2]; l.w = ll[3];
        ((ushort4*)ph)[i] = h;
        ((ushort4*)pl)[i] = l;
    }
}

// ---------------------------------------------------------------------------
// Q/K projection, split-bf16 3-term MFMA. 128x128 tile, BK=32, 256 threads.
// q outputs prescaled by QSC so attention scores are already in log2 units.
// ---------------------------------------------------------------------------
__global__ __launch_bounds__(256) void proj_split(
    const float* __restrict__ x,
    const ushort_t* __restrict__ Wqh, const ushort_t* __restrict__ Wql,
    const ushort_t* __restrict__ Wkh, const ushort_t* __restrict__ Wkl,
    const float* __restrict__ bq, const float* __restrict__ bk,
    ushort_t* __restrict__ qh, ushort_t* __restrict__ ql,
    ushort_t* __restrict__ kh, ushort_t* __restrict__ kl)
{
    const int z = blockIdx.z;
    const ushort_t* Wh = z ? Wkh : Wqh;
    const ushort_t* Wl = z ? Wkl : Wql;
    const float* bias  = z ? bk  : bq;
    ushort_t* dh       = z ? kh  : qh;
    ushort_t* dl       = z ? kl  : ql;
    const float qs     = z ? 1.0f : QSC;

    const int n0 = blockIdx.y * 128;
    const int o0 = blockIdx.x * 128;

    __shared__ float    Asf[128 * 32];   // fp32 x tile
    __shared__ ushort_t Bsh[128 * 32];   // W hi
    __shared__ ushort_t Bsl[128 * 32];   // W lo

    const int t = threadIdx.x;
    const int lane = t & 63, w = t >> 6;
    const int ln = lane & 15, qd = lane >> 4;
    const int wy = w >> 1, wx = w & 1;

    int rxS[4], cxS[4];
    #pragma unroll
    for (int i = 0; i < 4; ++i) {
        int slot = i * 256 + t;
        rxS[i] = slot >> 3;
        cxS[i] = (slot & 7) ^ (rxS[i] & 7);
    }
    int rwS[2], cwS[2];
    #pragma unroll
    for (int i = 0; i < 2; ++i) {
        int slot = i * 256 + t;
        rwS[i] = slot >> 2;
        cwS[i] = (slot & 3) ^ ((rwS[i] >> 1) & 3);
    }

    f32x4 acc[4][4];
    #pragma unroll
    for (int i = 0; i < 4; ++i)
        #pragma unroll
        for (int j = 0; j < 4; ++j) acc[i][j] = (f32x4){0.f, 0.f, 0.f, 0.f};

    for (int k0 = 0; k0 < H_; k0 += 32) {
        __syncthreads();
        #pragma unroll
        for (int i = 0; i < 4; ++i)
            gload_lds16(x + (size_t)(n0 + rxS[i]) * H_ + k0 + cxS[i] * 4,
                        &Asf[i * 1024 + (t & ~63) * 4]);
        #pragma unroll
        for (int i = 0; i < 2; ++i) {
            gload_lds16(Wh + (size_t)(o0 + rwS[i]) * H_ + k0 + cwS[i] * 8,
                        &Bsh[i * 2048 + (t & ~63) * 8]);
            gload_lds16(Wl + (size_t)(o0 + rwS[i]) * H_ + k0 + cwS[i] * 8,
                        &Bsl[i * 2048 + (t & ~63) * 8]);
        }
        __syncthreads();

        short8 bh4[4], bl4[4];
        #pragma unroll
        for (int nt = 0; nt < 4; ++nt) {
            int row = wx * 64 + nt * 16 + ln;
            int sz = (qd ^ ((row >> 1) & 3)) << 3;
            bh4[nt] = *(const short8*)&Bsh[row * 32 + sz];
            bl4[nt] = *(const short8*)&Bsl[row * 32 + sz];
        }
        #pragma unroll
        for (int mt = 0; mt < 4; ++mt) {
            int row = wy * 64 + mt * 16 + ln;
            int r7 = row & 7;
            float4 fa = *(const float4*)&Asf[row * 32 + (((2 * qd)     ^ r7) << 2)];
            float4 fb = *(const float4*)&Asf[row * 32 + (((2 * qd + 1) ^ r7) << 2)];
            short8 ah, al;
            split8(fa, fb, ah, al);
            #pragma unroll
            for (int nt = 0; nt < 4; ++nt) {
                acc[mt][nt] = __builtin_amdgcn_mfma_f32_16x16x32_bf16(al, bh4[nt], acc[mt][nt], 0, 0, 0);
                acc[mt][nt] = __builtin_amdgcn_mfma_f32_16x16x32_bf16(ah, bl4[nt], acc[mt][nt], 0, 0, 0);
                acc[mt][nt] = __builtin_amdgcn_mfma_f32_16x16x32_bf16(ah, bh4[nt], acc[mt][nt], 0, 0, 0);
            }
        }
    }

    #pragma unroll
    for (int nt = 0; nt < 4; ++nt) {
        int o = o0 + wx * 64 + nt * 16 + ln;
        float bvv = bias[o];
        int hh = o >> 6, d = o & 63;
        #pragma unroll
        for (int mt = 0; mt < 4; ++mt) {
            #pragma unroll
            for (int r = 0; r < 4; ++r) {
                int n = n0 + wy * 64 + mt * 16 + qd * 4 + r;
                int bb = n >> 11, l = n & (L_ - 1);
                float val = (acc[mt][nt][r] + bvv) * qs;
                ushort_t vh = f2b(val);
                ushort_t vl = f2b(val - b2f(vh));
                size_t idx = (((size_t)(bb * NH_ + hh) * L_ + l) << 6) + d;
                dh[idx] = vh;
                dl[idx] = vl;
            }
        }
    }
}

// ---------------------------------------------------------------------------
// Attention column sums cs[b,h,k] = sum_q P[q,k].
// pass1 (denominator l): hi*hi scores only (bf16 accuracy suffices for l:
//   error averages down ~1/sqrt(N_eff) per row and again over q in outputs),
//   stages only Ksh -> 2 MFMAs/nt, half the LDS/fetch traffic.
// pass2 (numerators): full split-bf16 6-MFMA scores, exact probs -> colsums.
// exp via raw v_exp_f32 builtin (q prescaled by 0.125*log2e).
// ---------------------------------------------------------------------------
__global__ __launch_bounds__(256) void attn_split(
    const ushort_t* __restrict__ qh, const ushort_t* __restrict__ ql,
    const ushort_t* __restrict__ kh, const ushort_t* __restrict__ kl,
    float* __restrict__ cs)
{
    const int qt = blockIdx.x & 31;
    const int bh = blockIdx.x >> 5;

    const int t = threadIdx.x;
    const int lane = t & 63, w = t >> 6;
    const int ln = lane & 15, qd = lane >> 4;

    __shared__ ushort_t Ksh[64 * 64];
    __shared__ ushort_t Ksl[64 * 64];
    __shared__ float cs_all[4][64];

    const size_t headoff = (size_t)bh * L_ * DK_;
    const size_t qoff = headoff + ((size_t)(qt * 64 + w * 16 + ln)) * DK_;
    const short8 aq0h = *(const short8*)(qh + qoff + qd * 8);
    const short8 aq1h = *(const short8*)(qh + qoff + 32 + qd * 8);
    const short8 aq0l = *(const short8*)(ql + qoff + qd * 8);
    const short8 aq1l = *(const short8*)(ql + qoff + 32 + qd * 8);

    int rowS[2], cS[2];
    #pragma unroll
    for (int i = 0; i < 2; ++i) {
        int slot = i * 256 + t;
        rowS[i] = slot >> 3;
        cS[i] = (slot & 7) ^ (rowS[i] & 7);
    }

    float l_run[4] = {0.f, 0.f, 0.f, 0.f};

    // ---------------- pass 1: l = sum_k exp2(s_hi) ----------------
    for (int kt = 0; kt < 32; ++kt) {
        __syncthreads();
        #pragma unroll
        for (int i = 0; i < 2; ++i)
            gload_lds16(kh + headoff + ((size_t)(kt * 64 + rowS[i]) << 6) + cS[i] * 8,
                        &Ksh[i * 2048 + (t & ~63) * 8]);
        __syncthreads();

        #pragma unroll
        for (int nt = 0; nt < 4; ++nt) {
            int kr = nt * 16 + ln;
            int sz0 = ((qd     ^ (kr & 7)) << 3);
            int sz1 = (((qd + 4) ^ (kr & 7)) << 3);
            short8 b0h = *(const short8*)&Ksh[kr * 64 + sz0];
            short8 b1h = *(const short8*)&Ksh[kr * 64 + sz1];
            f32x4 zz = (f32x4){0.f, 0.f, 0.f, 0.f};
            zz = __builtin_amdgcn_mfma_f32_16x16x32_bf16(aq0h, b0h, zz, 0, 0, 0);
            zz = __builtin_amdgcn_mfma_f32_16x16x32_bf16(aq1h, b1h, zz, 0, 0, 0);
            #pragma unroll
            for (int r = 0; r < 4; ++r)
                l_run[r] += fexp2(zz[r]);
        }
    }

    #pragma unroll
    for (int off = 1; off < 16; off <<= 1)
        #pragma unroll
        for (int r = 0; r < 4; ++r)
            l_run[r] += __shfl_xor(l_run[r], off);
    float inv_l[4];
    #pragma unroll
    for (int r = 0; r < 4; ++r) inv_l[r] = 1.0f / l_run[r];

    // ---------------- pass 2: column sums (full precision) ----------------
    for (int kt = 0; kt < 32; ++kt) {
        __syncthreads();
        #pragma unroll
        for (int i = 0; i < 2; ++i) {
            gload_lds16(kh + headoff + ((size_t)(kt * 64 + rowS[i]) << 6) + cS[i] * 8,
                        &Ksh[i * 2048 + (t & ~63) * 8]);
            gload_lds16(kl + headoff + ((size_t)(kt * 64 + rowS[i]) << 6) + cS[i] * 8,
                        &Ksl[i * 2048 + (t & ~63) * 8]);
        }
        __syncthreads();

        float colp[4];
        #pragma unroll
        for (int nt = 0; nt < 4; ++nt) {
            int kr = nt * 16 + ln;
            int sz0 = ((qd     ^ (kr & 7)) << 3);
            int sz1 = (((qd + 4) ^ (kr & 7)) << 3);
            short8 b0h = *(const short8*)&Ksh[kr * 64 + sz0];
            short8 b1h = *(const short8*)&Ksh[kr * 64 + sz1];
            short8 b0l = *(const short8*)&Ksl[kr * 64 + sz0];
            short8 b1l = *(const short8*)&Ksl[kr * 64 + sz1];
            f32x4 zz = (f32x4){0.f, 0.f, 0.f, 0.f};
            zz = __builtin_amdgcn_mfma_f32_16x16x32_bf16(aq0l, b0h, zz, 0, 0, 0);
            zz = __builtin_amdgcn_mfma_f32_16x16x32_bf16(aq1l, b1h, zz, 0, 0, 0);
            zz = __builtin_amdgcn_mfma_f32_16x16x32_bf16(aq0h, b0l, zz, 0, 0, 0);
            zz = __builtin_amdgcn_mfma_f32_16x16x32_bf16(aq1h, b1l, zz, 0, 0, 0);
            zz = __builtin_amdgcn_mfma_f32_16x16x32_bf16(aq0h, b0h, zz, 0, 0, 0);
            zz = __builtin_amdgcn_mfma_f32_16x16x32_bf16(aq1h, b1h, zz, 0, 0, 0);
            colp[nt] = fexp2(zz[0]) * inv_l[0] + fexp2(zz[1]) * inv_l[1]
                     + fexp2(zz[2]) * inv_l[2] + fexp2(zz[3]) * inv_l[3];
        }
        #pragma unroll
        for (int nt = 0; nt < 4; ++nt) {
            colp[nt] += __shfl_xor(colp[nt], 16);
            colp[nt] += __shfl_xor(colp[nt], 32);
        }
        float mine = (qd == 0) ? colp[0] : (qd == 1) ? colp[1] : (qd == 2) ? colp[2] : colp[3];
        cs_all[w][lane] = mine;
        __syncthreads();
        if (t < 64) {
            float tot = cs_all[0][t] + cs_all[1][t] + cs_all[2][t] + cs_all[3][t];
            atomicAdd(&cs[(size_t)bh * L_ + kt * 64 + t], tot);
        }
    }
}

// ---------------------------------------------------------------------------
// T[b,h,h'] = sum_l cs[b,h,l] * x[b,l,h']   (fp32, atomic over 8 l-splits)
// ---------------------------------------------------------------------------
__global__ __launch_bounds__(256) void ctx1_kernel(
    const float* __restrict__ cs, const float* __restrict__ x, float* __restrict__ T)
{
    const int o0 = blockIdx.x * 64, b = blockIdx.y, l0 = blockIdx.z * 256;
    const int t = threadIdx.x, o = t & 63, hg = t >> 6;
    __shared__ float cs_s[16][128];
    float acc[4] = {};

    for (int ch = 0; ch < 2; ++ch) {
        int lbase = l0 + ch * 128;
        __syncthreads();
        for (int i = t; i < 2048; i += 256) {
            int h = i >> 7, lc = i & 127;
            cs_s[h][lc] = cs[((size_t)(b * NH_ + h) << 11) + lbase + lc];
        }
        __syncthreads();
        for (int lc = 0; lc < 128; ++lc) {
            float xv = x[((size_t)(b * L_ + lbase + lc) << 10) + o0 + o];
            #pragma unroll
            for (int j = 0; j < 4; ++j) acc[j] += cs_s[hg * 4 + j][lc] * xv;
        }
    }
    #pragma unroll
    for (int j = 0; j < 4; ++j)
        atomicAdd(&T[((size_t)(b * NH_ + hg * 4 + j) << 10) + o0 + o], acc[j]);
}

// ---------------------------------------------------------------------------
// ctx[b,o] = sum_h' T[b, o>>6, h'] * Wv[o,h'] + L*bv[o]; wave per row
// ---------------------------------------------------------------------------
__global__ __launch_bounds__(256) void ctx2_kernel(
    const float* __restrict__ T, const float* __restrict__ Wv,
    const float* __restrict__ bv, float* __restrict__ ctx)
{
    const int gid  = blockIdx.x * 4 + (threadIdx.x >> 6);   // 0..4095
    const int lane = threadIdx.x & 63;
    const int b = gid >> 10, o = gid & (H_ - 1);
    const float4* wr = (const float4*)(Wv + (size_t)o * H_);
    const float4* tr = (const float4*)(T + ((size_t)(b * NH_ + (o >> 6)) << 10));
    float acc = 0.f;
    #pragma unroll
    for (int i = 0; i < 4; ++i) {
        float4 wv = wr[lane + i * 64];
        float4 tv = tr[lane + i * 64];
        acc += wv.x * tv.x + wv.y * tv.y + wv.z * tv.z + wv.w * tv.w;
    }
    #pragma unroll
    for (int off = 32; off; off >>= 1) acc += __shfl_xor(acc, off);
    if (lane == 0) ctx[(b << 10) + o] = acc + (float)L_ * bv[o];
}

// ---------------------------------------------------------------------------
// pooled[b,o] = bo[o] + (1/L) * sum_h ctx[b,h] * Wo[o,h]; wave per row
// ---------------------------------------------------------------------------
__global__ __launch_bounds__(256) void pooled_kernel(
    const float* __restrict__ ctx, const float* __restrict__ Wo,
    const float* __restrict__ bo, float* __restrict__ out)
{
    const int gid  = blockIdx.x * 4 + (threadIdx.x >> 6);   // 0..4095
    const int lane = threadIdx.x & 63;
    const int b = gid >> 10, o = gid & (H_ - 1);
    const float4* wr = (const float4*)(Wo + (size_t)o * H_);
    const float4* cr = (const float4*)(ctx + ((size_t)b << 10));
    float acc = 0.f;
    #pragma unroll
    for (int i = 0; i < 4; ++i) {
        float4 wv = wr[lane + i * 64];
        float4 cv = cr[lane + i * 64];
        acc += wv.x * cv.x + wv.y * cv.y + wv.z * cv.z + wv.w * cv.w;
    }
    #pragma unroll
    for (int off = 32; off; off >>= 1) acc += __shfl_xor(acc, off);
    if (lane == 0) out[(b << 10) + o] = acc * (1.0f / (float)L_) + bo[o];
}

__global__ void weights_kernel(const float* __restrict__ cs, float* __restrict__ out)
{
    int i = blockIdx.x * 256 + threadIdx.x;   // 8192
    int b = i >> 11, k = i & (L_ - 1);
    float s = 0.f;
    #pragma unroll
    for (int h = 0; h < NH_; ++h) s += cs[((size_t)(b * NH_ + h) << 11) + k];
    out[B_ * H_ + i] = s * (1.0f / (float)(NH_ * L_));
}

// ---------------------------------------------------------------------------
extern "C" void kernel_launch(void* const* d_in, const int* in_sizes, int n_in,
                              void* d_out, int out_size, void* d_ws, size_t ws_size,
                              hipStream_t stream)
{
    const float* x  = (const float*)d_in[0];
    const float* Wq = (const float*)d_in[1];
    const float* bq = (const float*)d_in[2];
    const float* Wk = (const float*)d_in[3];
    const float* bk = (const float*)d_in[4];
    const float* Wv = (const float*)d_in[5];
    const float* bv = (const float*)d_in[6];
    const float* Wo = (const float*)d_in[7];
    const float* bo = (const float*)d_in[8];
    float* out = (float*)d_out;

    float* ws  = (float*)d_ws;
    float* cs  = ws;                       // B*NH*L = 131072 f
    float* T   = ws + 131072;              // B*NH*H =  65536 f
    float* ctx = ws + 196608;              // B*H    =   4096 f
    ushort_t* base = (ushort_t*)(ws + 200704);
    const size_t QE = 8388608;             // B*NH*L*DK
    ushort_t* qhb = base;
    ushort_t* qlb = base + QE;
    ushort_t* khb = base + 2 * QE;
    ushort_t* klb = base + 3 * QE;
    ushort_t* wqh = base + 4 * QE;
    ushort_t* wql = wqh + 1048576;
    ushort_t* wkh = wql + 1048576;
    ushort_t* wkl = wkh + 1048576;

    hipMemsetAsync(ws, 0, (131072 + 65536) * sizeof(float), stream);

    wsplit_kernel<<<1024, 256, 0, stream>>>(Wq, wqh, wql, 262144);
    wsplit_kernel<<<1024, 256, 0, stream>>>(Wk, wkh, wkl, 262144);

    proj_split<<<dim3(8, 64, 2), 256, 0, stream>>>(x, wqh, wql, wkh, wkl, bq, bk,
                                                   qhb, qlb, khb, klb);

    attn_split<<<B_ * NH_ * (L_ / 64), 256, 0, stream>>>(qhb, qlb, khb, klb, cs);

    ctx1_kernel<<<dim3(16, 4, 8), 256, 0, stream>>>(cs, x, T);
    ctx2_kernel<<<1024, 256, 0, stream>>>(T, Wv, bv, ctx);
    pooled_kernel<<<1024, 256, 0, stream>>>(ctx, Wo, bo, out);
    weights_kernel<<<(B_ * L_) / 256, 256, 0, stream>>>(cs, out);
}

// Round 7
// 385.974 us; speedup vs baseline: 6.9908x; 1.1172x over previous
//
#include <hip/hip_runtime.h>
#include <math.h>

#define B_  4
#define L_  2048
#define H_  1024
#define NH_ 16
#define DK_ 64

// 0.125 * log2(e): folded into q so attn scores are already in log2 units
#define QSC 0.18033688011112043f

typedef unsigned short ushort_t;
typedef __attribute__((ext_vector_type(8))) short short8;
typedef __attribute__((ext_vector_type(4))) float f32x4;

__device__ __forceinline__ ushort_t f2b(float f) {   // RNE fp32->bf16
    unsigned int u = __float_as_uint(f);
    return (ushort_t)((u + 0x7FFFu + ((u >> 16) & 1u)) >> 16);
}
__device__ __forceinline__ float b2f(ushort_t h) {
    return __uint_as_float(((unsigned int)h) << 16);
}
// raw v_exp_f32 (2^x), no libm range fixup
__device__ __forceinline__ float fexp2(float x) {
    return __builtin_amdgcn_exp2f(x);
}

__device__ __forceinline__ void gload_lds16(const void* g, void* l) {
    __builtin_amdgcn_global_load_lds((const __attribute__((address_space(1))) void*)g,
                                     (__attribute__((address_space(3))) void*)l, 16, 0, 0);
}

// trunc-split 8 fp32 -> (hi, lo) bf16 frags
__device__ __forceinline__ void split8(const float4& a, const float4& b,
                                       short8& h, short8& l) {
    float f[8] = {a.x, a.y, a.z, a.w, b.x, b.y, b.z, b.w};
    #pragma unroll
    for (int e = 0; e < 8; ++e) {
        unsigned int u  = __float_as_uint(f[e]);
        float fh = __uint_as_float(u & 0xFFFF0000u);
        float r  = f[e] - fh;
        h[e] = (short)(u >> 16);
        l[e] = (short)(__float_as_uint(r) >> 16);
    }
}

// ---------------------------------------------------------------------------
// RNE split cast for weights: src fp32 -> (hi, lo) bf16 planes
// ---------------------------------------------------------------------------
__global__ __launch_bounds__(256) void wsplit_kernel(const float* __restrict__ src,
                                                     ushort_t* __restrict__ ph,
                                                     ushort_t* __restrict__ pl, int n4)
{
    int i = blockIdx.x * 256 + threadIdx.x;
    if (i < n4) {
        float4 v = ((const float4*)src)[i];
        ushort4 h, l;
        float f[4] = {v.x, v.y, v.z, v.w};
        ushort_t hh[4], ll[4];
        #pragma unroll
        for (int e = 0; e < 4; ++e) {
            hh[e] = f2b(f[e]);
            ll[e] = f2b(f[e] - b2f(hh[e]));
        }
        h.x = hh[0]; h.y = hh[1]; h.z = hh[2]; h.w = hh[3];
        l.x = ll[0]; l.y = ll[1]; l.z = ll[2]; l.w = ll[3];
        ((ushort4*)ph)[i] = h;
        ((ushort4*)pl)[i] = l;
    }
}

// ---------------------------------------------------------------------------
// Q/K projection, split-bf16 3-term MFMA. 128x128 tile, BK=32, 256 threads.
// q outputs prescaled by QSC so attention scores are already in log2 units.
// ---------------------------------------------------------------------------
__global__ __launch_bounds__(256) void proj_split(
    const float* __restrict__ x,
    const ushort_t* __restrict__ Wqh, const ushort_t* __restrict__ Wql,
    const ushort_t* __restrict__ Wkh, const ushort_t* __restrict__ Wkl,
    const float* __restrict__ bq, const float* __restrict__ bk,
    ushort_t* __restrict__ qh, ushort_t* __restrict__ ql,
    ushort_t* __restrict__ kh, ushort_t* __restrict__ kl)
{
    const int z = blockIdx.z;
    const ushort_t* Wh = z ? Wkh : Wqh;
    const ushort_t* Wl = z ? Wkl : Wql;
    const float* bias  = z ? bk  : bq;
    ushort_t* dh       = z ? kh  : qh;
    ushort_t* dl       = z ? kl  : ql;
    const float qs     = z ? 1.0f : QSC;

    const int n0 = blockIdx.y * 128;
    const int o0 = blockIdx.x * 128;

    __shared__ float    Asf[128 * 32];   // fp32 x tile
    __shared__ ushort_t Bsh[128 * 32];   // W hi
    __shared__ ushort_t Bsl[128 * 32];   // W lo

    const int t = threadIdx.x;
    const int lane = t & 63, w = t >> 6;
    const int ln = lane & 15, qd = lane >> 4;
    const int wy = w >> 1, wx = w & 1;

    int rxS[4], cxS[4];
    #pragma unroll
    for (int i = 0; i < 4; ++i) {
        int slot = i * 256 + t;
        rxS[i] = slot >> 3;
        cxS[i] = (slot & 7) ^ (rxS[i] & 7);
    }
    int rwS[2], cwS[2];
    #pragma unroll
    for (int i = 0; i < 2; ++i) {
        int slot = i * 256 + t;
        rwS[i] = slot >> 2;
        cwS[i] = (slot & 3) ^ ((rwS[i] >> 1) & 3);
    }

    f32x4 acc[4][4];
    #pragma unroll
    for (int i = 0; i < 4; ++i)
        #pragma unroll
        for (int j = 0; j < 4; ++j) acc[i][j] = (f32x4){0.f, 0.f, 0.f, 0.f};

    for (int k0 = 0; k0 < H_; k0 += 32) {
        __syncthreads();
        #pragma unroll
        for (int i = 0; i < 4; ++i)
            gload_lds16(x + (size_t)(n0 + rxS[i]) * H_ + k0 + cxS[i] * 4,
                        &Asf[i * 1024 + (t & ~63) * 4]);
        #pragma unroll
        for (int i = 0; i < 2; ++i) {
            gload_lds16(Wh + (size_t)(o0 + rwS[i]) * H_ + k0 + cwS[i] * 8,
                        &Bsh[i * 2048 + (t & ~63) * 8]);
            gload_lds16(Wl + (size_t)(o0 + rwS[i]) * H_ + k0 + cwS[i] * 8,
                        &Bsl[i * 2048 + (t & ~63) * 8]);
        }
        __syncthreads();

        short8 bh4[4], bl4[4];
        #pragma unroll
        for (int nt = 0; nt < 4; ++nt) {
            int row = wx * 64 + nt * 16 + ln;
            int sz = (qd ^ ((row >> 1) & 3)) << 3;
            bh4[nt] = *(const short8*)&Bsh[row * 32 + sz];
            bl4[nt] = *(const short8*)&Bsl[row * 32 + sz];
        }
        #pragma unroll
        for (int mt = 0; mt < 4; ++mt) {
            int row = wy * 64 + mt * 16 + ln;
            int r7 = row & 7;
            float4 fa = *(const float4*)&Asf[row * 32 + (((2 * qd)     ^ r7) << 2)];
            float4 fb = *(const float4*)&Asf[row * 32 + (((2 * qd + 1) ^ r7) << 2)];
            short8 ah, al;
            split8(fa, fb, ah, al);
            #pragma unroll
            for (int nt = 0; nt < 4; ++nt) {
                acc[mt][nt] = __builtin_amdgcn_mfma_f32_16x16x32_bf16(al, bh4[nt], acc[mt][nt], 0, 0, 0);
                acc[mt][nt] = __builtin_amdgcn_mfma_f32_16x16x32_bf16(ah, bl4[nt], acc[mt][nt], 0, 0, 0);
                acc[mt][nt] = __builtin_amdgcn_mfma_f32_16x16x32_bf16(ah, bh4[nt], acc[mt][nt], 0, 0, 0);
            }
        }
    }

    #pragma unroll
    for (int nt = 0; nt < 4; ++nt) {
        int o = o0 + wx * 64 + nt * 16 + ln;
        float bvv = bias[o];
        int hh = o >> 6, d = o & 63;
        #pragma unroll
        for (int mt = 0; mt < 4; ++mt) {
            #pragma unroll
            for (int r = 0; r < 4; ++r) {
                int n = n0 + wy * 64 + mt * 16 + qd * 4 + r;
                int bb = n >> 11, l = n & (L_ - 1);
                float val = (acc[mt][nt][r] + bvv) * qs;
                ushort_t vh = f2b(val);
                ushort_t vl = f2b(val - b2f(vh));
                size_t idx = (((size_t)(bb * NH_ + hh) * L_ + l) << 6) + d;
                dh[idx] = vh;
                dl[idx] = vl;
            }
        }
    }
}

// ---------------------------------------------------------------------------
// Attention column sums cs[b,h,k] = sum_q P[q,k].
// q-tile 128/block: each wave holds TWO 16-row A-frag sets (32 q-rows) and
// reuses every K B-frag ds_read for both -> LDS read bytes per q halved.
// pass1: hi*hi denominators; pass2: full split-bf16 6-MFMA numerators.
// ---------------------------------------------------------------------------
__global__ __launch_bounds__(256) void attn_split(
    const ushort_t* __restrict__ qh, const ushort_t* __restrict__ ql,
    const ushort_t* __restrict__ kh, const ushort_t* __restrict__ kl,
    float* __restrict__ cs)
{
    const int qt = blockIdx.x & 15;        // 16 q-tiles of 128 rows
    const int bh = blockIdx.x >> 4;

    const int t = threadIdx.x;
    const int lane = t & 63, w = t >> 6;
    const int ln = lane & 15, qd = lane >> 4;

    __shared__ ushort_t Ksh[64 * 64];
    __shared__ ushort_t Ksl[64 * 64];
    __shared__ float cs_all[4][64];

    const size_t headoff = (size_t)bh * L_ * DK_;
    // two q-row sets per wave: rows qt*128 + w*32 + ln and +16
    const size_t qoff0 = headoff + ((size_t)(qt * 128 + w * 32 + ln)) * DK_;
    const size_t qoff1 = qoff0 + 16 * DK_;
    short8 aqh[2][2], aql[2][2];
    aqh[0][0] = *(const short8*)(qh + qoff0 + qd * 8);
    aqh[0][1] = *(const short8*)(qh + qoff0 + 32 + qd * 8);
    aqh[1][0] = *(const short8*)(qh + qoff1 + qd * 8);
    aqh[1][1] = *(const short8*)(qh + qoff1 + 32 + qd * 8);
    aql[0][0] = *(const short8*)(ql + qoff0 + qd * 8);
    aql[0][1] = *(const short8*)(ql + qoff0 + 32 + qd * 8);
    aql[1][0] = *(const short8*)(ql + qoff1 + qd * 8);
    aql[1][1] = *(const short8*)(ql + qoff1 + 32 + qd * 8);

    int rowS[2], cS[2];
    #pragma unroll
    for (int i = 0; i < 2; ++i) {
        int slot = i * 256 + t;
        rowS[i] = slot >> 3;
        cS[i] = (slot & 7) ^ (rowS[i] & 7);
    }

    float l_run[2][4] = {};

    // ---------------- pass 1: l = sum_k exp2(s_hi) ----------------
    for (int kt = 0; kt < 32; ++kt) {
        __syncthreads();
        #pragma unroll
        for (int i = 0; i < 2; ++i)
            gload_lds16(kh + headoff + ((size_t)(kt * 64 + rowS[i]) << 6) + cS[i] * 8,
                        &Ksh[i * 2048 + (t & ~63) * 8]);
        __syncthreads();

        #pragma unroll
        for (int nt = 0; nt < 4; ++nt) {
            int kr = nt * 16 + ln;
            int sz0 = ((qd     ^ (kr & 7)) << 3);
            int sz1 = (((qd + 4) ^ (kr & 7)) << 3);
            short8 b0h = *(const short8*)&Ksh[kr * 64 + sz0];
            short8 b1h = *(const short8*)&Ksh[kr * 64 + sz1];
            #pragma unroll
            for (int s = 0; s < 2; ++s) {
                f32x4 zz = (f32x4){0.f, 0.f, 0.f, 0.f};
                zz = __builtin_amdgcn_mfma_f32_16x16x32_bf16(aqh[s][0], b0h, zz, 0, 0, 0);
                zz = __builtin_amdgcn_mfma_f32_16x16x32_bf16(aqh[s][1], b1h, zz, 0, 0, 0);
                #pragma unroll
                for (int r = 0; r < 4; ++r)
                    l_run[s][r] += fexp2(zz[r]);
            }
        }
    }

    #pragma unroll
    for (int off = 1; off < 16; off <<= 1)
        #pragma unroll
        for (int s = 0; s < 2; ++s)
            #pragma unroll
            for (int r = 0; r < 4; ++r)
                l_run[s][r] += __shfl_xor(l_run[s][r], off);
    float inv_l[2][4];
    #pragma unroll
    for (int s = 0; s < 2; ++s)
        #pragma unroll
        for (int r = 0; r < 4; ++r) inv_l[s][r] = 1.0f / l_run[s][r];

    // ---------------- pass 2: column sums (full precision) ----------------
    for (int kt = 0; kt < 32; ++kt) {
        __syncthreads();
        #pragma unroll
        for (int i = 0; i < 2; ++i) {
            gload_lds16(kh + headoff + ((size_t)(kt * 64 + rowS[i]) << 6) + cS[i] * 8,
                        &Ksh[i * 2048 + (t & ~63) * 8]);
            gload_lds16(kl + headoff + ((size_t)(kt * 64 + rowS[i]) << 6) + cS[i] * 8,
                        &Ksl[i * 2048 + (t & ~63) * 8]);
        }
        __syncthreads();

        float colp[4];
        #pragma unroll
        for (int nt = 0; nt < 4; ++nt) {
            int kr = nt * 16 + ln;
            int sz0 = ((qd     ^ (kr & 7)) << 3);
            int sz1 = (((qd + 4) ^ (kr & 7)) << 3);
            short8 b0h = *(const short8*)&Ksh[kr * 64 + sz0];
            short8 b1h = *(const short8*)&Ksh[kr * 64 + sz1];
            short8 b0l = *(const short8*)&Ksl[kr * 64 + sz0];
            short8 b1l = *(const short8*)&Ksl[kr * 64 + sz1];
            float cp = 0.f;
            #pragma unroll
            for (int s = 0; s < 2; ++s) {
                f32x4 zz = (f32x4){0.f, 0.f, 0.f, 0.f};
                zz = __builtin_amdgcn_mfma_f32_16x16x32_bf16(aql[s][0], b0h, zz, 0, 0, 0);
                zz = __builtin_amdgcn_mfma_f32_16x16x32_bf16(aql[s][1], b1h, zz, 0, 0, 0);
                zz = __builtin_amdgcn_mfma_f32_16x16x32_bf16(aqh[s][0], b0l, zz, 0, 0, 0);
                zz = __builtin_amdgcn_mfma_f32_16x16x32_bf16(aqh[s][1], b1l, zz, 0, 0, 0);
                zz = __builtin_amdgcn_mfma_f32_16x16x32_bf16(aqh[s][0], b0h, zz, 0, 0, 0);
                zz = __builtin_amdgcn_mfma_f32_16x16x32_bf16(aqh[s][1], b1h, zz, 0, 0, 0);
                cp += fexp2(zz[0]) * inv_l[s][0] + fexp2(zz[1]) * inv_l[s][1]
                    + fexp2(zz[2]) * inv_l[s][2] + fexp2(zz[3]) * inv_l[s][3];
            }
            colp[nt] = cp;
        }
        #pragma unroll
        for (int nt = 0; nt < 4; ++nt) {
            colp[nt] += __shfl_xor(colp[nt], 16);
            colp[nt] += __shfl_xor(colp[nt], 32);
        }
        float mine = (qd == 0) ? colp[0] : (qd == 1) ? colp[1] : (qd == 2) ? colp[2] : colp[3];
        cs_all[w][lane] = mine;
        __syncthreads();
        if (t < 64) {
            float tot = cs_all[0][t] + cs_all[1][t] + cs_all[2][t] + cs_all[3][t];
            atomicAdd(&cs[(size_t)bh * L_ + kt * 64 + t], tot);
        }
    }
}

// ---------------------------------------------------------------------------
// T[b,h,h'] = sum_l cs[b,h,l] * x[b,l,h']   (fp32, atomic over 8 l-splits)
// ---------------------------------------------------------------------------
__global__ __launch_bounds__(256) void ctx1_kernel(
    const float* __restrict__ cs, const float* __restrict__ x, float* __restrict__ T)
{
    const int o0 = blockIdx.x * 64, b = blockIdx.y, l0 = blockIdx.z * 256;
    const int t = threadIdx.x, o = t & 63, hg = t >> 6;
    __shared__ float cs_s[16][128];
    float acc[4] = {};

    for (int ch = 0; ch < 2; ++ch) {
        int lbase = l0 + ch * 128;
        __syncthreads();
        for (int i = t; i < 2048; i += 256) {
            int h = i >> 7, lc = i & 127;
            cs_s[h][lc] = cs[((size_t)(b * NH_ + h) << 11) + lbase + lc];
        }
        __syncthreads();
        for (int lc = 0; lc < 128; ++lc) {
            float xv = x[((size_t)(b * L_ + lbase + lc) << 10) + o0 + o];
            #pragma unroll
            for (int j = 0; j < 4; ++j) acc[j] += cs_s[hg * 4 + j][lc] * xv;
        }
    }
    #pragma unroll
    for (int j = 0; j < 4; ++j)
        atomicAdd(&T[((size_t)(b * NH_ + hg * 4 + j) << 10) + o0 + o], acc[j]);
}

// ---------------------------------------------------------------------------
// ctx[b,o] = sum_h' T[b, o>>6, h'] * Wv[o,h'] + L*bv[o]; wave per row
// ---------------------------------------------------------------------------
__global__ __launch_bounds__(256) void ctx2_kernel(
    const float* __restrict__ T, const float* __restrict__ Wv,
    const float* __restrict__ bv, float* __restrict__ ctx)
{
    const int gid  = blockIdx.x * 4 + (threadIdx.x >> 6);   // 0..4095
    const int lane = threadIdx.x & 63;
    const int b = gid >> 10, o = gid & (H_ - 1);
    const float4* wr = (const float4*)(Wv + (size_t)o * H_);
    const float4* tr = (const float4*)(T + ((size_t)(b * NH_ + (o >> 6)) << 10));
    float acc = 0.f;
    #pragma unroll
    for (int i = 0; i < 4; ++i) {
        float4 wv = wr[lane + i * 64];
        float4 tv = tr[lane + i * 64];
        acc += wv.x * tv.x + wv.y * tv.y + wv.z * tv.z + wv.w * tv.w;
    }
    #pragma unroll
    for (int off = 32; off; off >>= 1) acc += __shfl_xor(acc, off);
    if (lane == 0) ctx[(b << 10) + o] = acc + (float)L_ * bv[o];
}

// ---------------------------------------------------------------------------
// pooled[b,o] = bo[o] + (1/L) * sum_h ctx[b,h] * Wo[o,h]; wave per row
// ---------------------------------------------------------------------------
__global__ __launch_bounds__(256) void pooled_kernel(
    const float* __restrict__ ctx, const float* __restrict__ Wo,
    const float* __restrict__ bo, float* __restrict__ out)
{
    const int gid  = blockIdx.x * 4 + (threadIdx.x >> 6);   // 0..4095
    const int lane = threadIdx.x & 63;
    const int b = gid >> 10, o = gid & (H_ - 1);
    const float4* wr = (const float4*)(Wo + (size_t)o * H_);
    const float4* cr = (const float4*)(ctx + ((size_t)b << 10));
    float acc = 0.f;
    #pragma unroll
    for (int i = 0; i < 4; ++i) {
        float4 wv = wr[lane + i * 64];
        float4 cv = cr[lane + i * 64];
        acc += wv.x * cv.x + wv.y * cv.y + wv.z * cv.z + wv.w * cv.w;
    }
    #pragma unroll
    for (int off = 32; off; off >>= 1) acc += __shfl_xor(acc, off);
    if (lane == 0) out[(b << 10) + o] = acc * (1.0f / (float)L_) + bo[o];
}

__global__ void weights_kernel(const float* __restrict__ cs, float* __restrict__ out)
{
    int i = blockIdx.x * 256 + threadIdx.x;   // 8192
    int b = i >> 11, k = i & (L_ - 1);
    float s = 0.f;
    #pragma unroll
    for (int h = 0; h < NH_; ++h) s += cs[((size_t)(b * NH_ + h) << 11) + k];
    out[B_ * H_ + i] = s * (1.0f / (float)(NH_ * L_));
}

// ---------------------------------------------------------------------------
extern "C" void kernel_launch(void* const* d_in, const int* in_sizes, int n_in,
                              void* d_out, int out_size, void* d_ws, size_t ws_size,
                              hipStream_t stream)
{
    const float* x  = (const float*)d_in[0];
    const float* Wq = (const float*)d_in[1];
    const float* bq = (const float*)d_in[2];
    const float* Wk = (const float*)d_in[3];
    const float* bk = (const float*)d_in[4];
    const float* Wv = (const float*)d_in[5];
    const float* bv = (const float*)d_in[6];
    const float* Wo = (const float*)d_in[7];
    const float* bo = (const float*)d_in[8];
    float* out = (float*)d_out;

    float* ws  = (float*)d_ws;
    float* cs  = ws;                       // B*NH*L = 131072 f
    float* T   = ws + 131072;              // B*NH*H =  65536 f
    float* ctx = ws + 196608;              // B*H    =   4096 f
    ushort_t* base = (ushort_t*)(ws + 200704);
    const size_t QE = 8388608;             // B*NH*L*DK
    ushort_t* qhb = base;
    ushort_t* qlb = base + QE;
    ushort_t* khb = base + 2 * QE;
    ushort_t* klb = base + 3 * QE;
    ushort_t* wqh = base + 4 * QE;
    ushort_t* wql = wqh + 1048576;
    ushort_t* wkh = wql + 1048576;
    ushort_t* wkl = wkh + 1048576;

    hipMemsetAsync(ws, 0, (131072 + 65536) * sizeof(float), stream);

    wsplit_kernel<<<1024, 256, 0, stream>>>(Wq, wqh, wql, 262144);
    wsplit_kernel<<<1024, 256, 0, stream>>>(Wk, wkh, wkl, 262144);

    proj_split<<<dim3(8, 64, 2), 256, 0, stream>>>(x, wqh, wql, wkh, wkl, bq, bk,
                                                   qhb, qlb, khb, klb);

    attn_split<<<B_ * NH_ * (L_ / 128), 256, 0, stream>>>(qhb, qlb, khb, klb, cs);

    ctx1_kernel<<<dim3(16, 4, 8), 256, 0, stream>>>(cs, x, T);
    ctx2_kernel<<<1024, 256, 0, stream>>>(T, Wv, bv, ctx);
    pooled_kernel<<<1024, 256, 0, stream>>>(ctx, Wo, bo, out);
    weights_kernel<<<(B_ * L_) / 256, 256, 0, stream>>>(cs, out);
}

// Round 8
// 366.013 us; speedup vs baseline: 7.3720x; 1.0545x over previous
//
#include <hip/hip_runtime.h>
#include <math.h>

#define B_  4
#define L_  2048
#define H_  1024
#define NH_ 16
#define DK_ 64

// 0.125 * log2(e): folded into q so attn scores are already in log2 units
#define QSC 0.18033688011112043f

typedef unsigned short ushort_t;
typedef __attribute__((ext_vector_type(8))) short short8;
typedef __attribute__((ext_vector_type(4))) float f32x4;

__device__ __forceinline__ ushort_t f2b(float f) {   // RNE fp32->bf16
    unsigned int u = __float_as_uint(f);
    return (ushort_t)((u + 0x7FFFu + ((u >> 16) & 1u)) >> 16);
}
__device__ __forceinline__ float b2f(ushort_t h) {
    return __uint_as_float(((unsigned int)h) << 16);
}
// raw v_exp_f32 (2^x), no libm range fixup
__device__ __forceinline__ float fexp2(float x) {
    return __builtin_amdgcn_exp2f(x);
}

__device__ __forceinline__ void gload_lds16(const void* g, void* l) {
    __builtin_amdgcn_global_load_lds((const __attribute__((address_space(1))) void*)g,
                                     (__attribute__((address_space(3))) void*)l, 16, 0, 0);
}

// ---------------------------------------------------------------------------
// RNE split cast: src fp32 -> (hi, lo) bf16 planes (used for W and x)
// ---------------------------------------------------------------------------
__global__ __launch_bounds__(256) void fsplit_kernel(const float* __restrict__ src,
                                                     ushort_t* __restrict__ ph,
                                                     ushort_t* __restrict__ pl, int n4)
{
    int i = blockIdx.x * 256 + threadIdx.x;
    if (i < n4) {
        float4 v = ((const float4*)src)[i];
        ushort4 h, l;
        float f[4] = {v.x, v.y, v.z, v.w};
        ushort_t hh[4], ll[4];
        #pragma unroll
        for (int e = 0; e < 4; ++e) {
            hh[e] = f2b(f[e]);
            ll[e] = f2b(f[e] - b2f(hh[e]));
        }
        h.x = hh[0]; h.y = hh[1]; h.z = hh[2]; h.w = hh[3];
        l.x = ll[0]; l.y = ll[1]; l.z = ll[2]; l.w = ll[3];
        ((ushort4*)ph)[i] = h;
        ((ushort4*)pl)[i] = l;
    }
}

// ---------------------------------------------------------------------------
// Q/K projection from pre-split x planes. 128x128 tile, BK=32, 256 threads.
// z=0 (q): 2 MFMAs (ah+al)*Wh, output hi only, prescaled by QSC.
// z=1 (k): 3 MFMAs (al*Wh + ah*Wl + ah*Wh), output split (hi,lo).
// ---------------------------------------------------------------------------
__global__ __launch_bounds__(256) void proj_split(
    const ushort_t* __restrict__ xh, const ushort_t* __restrict__ xl,
    const ushort_t* __restrict__ Wqh,
    const ushort_t* __restrict__ Wkh, const ushort_t* __restrict__ Wkl,
    const float* __restrict__ bq, const float* __restrict__ bk,
    ushort_t* __restrict__ qho,
    ushort_t* __restrict__ kho, ushort_t* __restrict__ klo)
{
    const int z = blockIdx.z;
    const ushort_t* Wh = z ? Wkh : Wqh;
    const ushort_t* Wl = Wkl;              // only staged/used when z==1
    const float* bias  = z ? bk  : bq;

    const int n0 = blockIdx.y * 128;
    const int o0 = blockIdx.x * 128;

    __shared__ ushort_t Ash[128 * 32];
    __shared__ ushort_t Asl[128 * 32];
    __shared__ ushort_t Bsh[128 * 32];
    __shared__ ushort_t Bsl[128 * 32];

    const int t = threadIdx.x;
    const int lane = t & 63, w = t >> 6;
    const int ln = lane & 15, qd = lane >> 4;
    const int wy = w >> 1, wx = w & 1;
    const int ldsbase = (t & ~63) * 8;     // wave-uniform ushort base

    // staging: slot = i*256 + t; row = slot>>2 (4 chunks of 8 ushorts per row)
    int rowS[2], cS[2];
    #pragma unroll
    for (int i = 0; i < 2; ++i) {
        int slot = i * 256 + t;
        rowS[i] = slot >> 2;
        cS[i] = (slot & 3) ^ ((rowS[i] >> 1) & 3);
    }

    f32x4 acc[4][4];
    #pragma unroll
    for (int i = 0; i < 4; ++i)
        #pragma unroll
        for (int j = 0; j < 4; ++j) acc[i][j] = (f32x4){0.f, 0.f, 0.f, 0.f};

    for (int k0 = 0; k0 < H_; k0 += 32) {
        __syncthreads();
        #pragma unroll
        for (int i = 0; i < 2; ++i) {
            gload_lds16(xh + (size_t)(n0 + rowS[i]) * H_ + k0 + cS[i] * 8,
                        &Ash[i * 2048 + ldsbase]);
            gload_lds16(xl + (size_t)(n0 + rowS[i]) * H_ + k0 + cS[i] * 8,
                        &Asl[i * 2048 + ldsbase]);
            gload_lds16(Wh + (size_t)(o0 + rowS[i]) * H_ + k0 + cS[i] * 8,
                        &Bsh[i * 2048 + ldsbase]);
        }
        if (z) {
            #pragma unroll
            for (int i = 0; i < 2; ++i)
                gload_lds16(Wl + (size_t)(o0 + rowS[i]) * H_ + k0 + cS[i] * 8,
                            &Bsl[i * 2048 + ldsbase]);
        }
        __syncthreads();

        short8 bh4[4], bl4[4];
        #pragma unroll
        for (int nt = 0; nt < 4; ++nt) {
            int row = wx * 64 + nt * 16 + ln;
            int sz = (qd ^ ((row >> 1) & 3)) << 3;
            bh4[nt] = *(const short8*)&Bsh[row * 32 + sz];
            if (z) bl4[nt] = *(const short8*)&Bsl[row * 32 + sz];
        }
        #pragma unroll
        for (int mt = 0; mt < 4; ++mt) {
            int row = wy * 64 + mt * 16 + ln;
            int sz = (qd ^ ((row >> 1) & 3)) << 3;
            short8 ah = *(const short8*)&Ash[row * 32 + sz];
            short8 al = *(const short8*)&Asl[row * 32 + sz];
            if (z) {
                #pragma unroll
                for (int nt = 0; nt < 4; ++nt) {
                    acc[mt][nt] = __builtin_amdgcn_mfma_f32_16x16x32_bf16(al, bh4[nt], acc[mt][nt], 0, 0, 0);
                    acc[mt][nt] = __builtin_amdgcn_mfma_f32_16x16x32_bf16(ah, bl4[nt], acc[mt][nt], 0, 0, 0);
                    acc[mt][nt] = __builtin_amdgcn_mfma_f32_16x16x32_bf16(ah, bh4[nt], acc[mt][nt], 0, 0, 0);
                }
            } else {
                #pragma unroll
                for (int nt = 0; nt < 4; ++nt) {
                    acc[mt][nt] = __builtin_amdgcn_mfma_f32_16x16x32_bf16(al, bh4[nt], acc[mt][nt], 0, 0, 0);
                    acc[mt][nt] = __builtin_amdgcn_mfma_f32_16x16x32_bf16(ah, bh4[nt], acc[mt][nt], 0, 0, 0);
                }
            }
        }
    }

    // epilogue: C row=(lane>>4)*4+reg (token), col=lane&15 (o)
    #pragma unroll
    for (int nt = 0; nt < 4; ++nt) {
        int o = o0 + wx * 64 + nt * 16 + ln;
        float bvv = bias[o];
        int hh = o >> 6, d = o & 63;
        #pragma unroll
        for (int mt = 0; mt < 4; ++mt) {
            #pragma unroll
            for (int r = 0; r < 4; ++r) {
                int n = n0 + wy * 64 + mt * 16 + qd * 4 + r;
                int bb = n >> 11, l = n & (L_ - 1);
                size_t idx = (((size_t)(bb * NH_ + hh) * L_ + l) << 6) + d;
                float val = acc[mt][nt][r] + bvv;
                if (z) {
                    ushort_t vh = f2b(val);
                    kho[idx] = vh;
                    klo[idx] = f2b(val - b2f(vh));
                } else {
                    qho[idx] = f2b(val * QSC);
                }
            }
        }
    }
}

// ---------------------------------------------------------------------------
// Attention column sums cs[b,h,k] = sum_q P[q,k]. q-tile 128/block, 2 A-sets
// per wave. pass1: qh*kh denominators (2 MFMA/nt/set). pass2: qh*(kh+kl)
// numerators (4 MFMA/nt/set) — k-lo kept (systematic across q), q-lo dropped
// (q-side errors average down ~1/sqrt(L) in both outputs).
// ---------------------------------------------------------------------------
__global__ __launch_bounds__(256) void attn_split(
    const ushort_t* __restrict__ qh,
    const ushort_t* __restrict__ kh, const ushort_t* __restrict__ kl,
    float* __restrict__ cs)
{
    const int qt = blockIdx.x & 15;        // 16 q-tiles of 128 rows
    const int bh = blockIdx.x >> 4;

    const int t = threadIdx.x;
    const int lane = t & 63, w = t >> 6;
    const int ln = lane & 15, qd = lane >> 4;

    __shared__ ushort_t Ksh[64 * 64];
    __shared__ ushort_t Ksl[64 * 64];
    __shared__ float cs_all[4][64];

    const size_t headoff = (size_t)bh * L_ * DK_;
    const size_t qoff0 = headoff + ((size_t)(qt * 128 + w * 32 + ln)) * DK_;
    const size_t qoff1 = qoff0 + 16 * DK_;
    short8 aqh[2][2];
    aqh[0][0] = *(const short8*)(qh + qoff0 + qd * 8);
    aqh[0][1] = *(const short8*)(qh + qoff0 + 32 + qd * 8);
    aqh[1][0] = *(const short8*)(qh + qoff1 + qd * 8);
    aqh[1][1] = *(const short8*)(qh + qoff1 + 32 + qd * 8);

    int rowS[2], cS[2];
    #pragma unroll
    for (int i = 0; i < 2; ++i) {
        int slot = i * 256 + t;
        rowS[i] = slot >> 3;
        cS[i] = (slot & 7) ^ (rowS[i] & 7);
    }

    float l_run[2][4] = {};

    // ---------------- pass 1: l = sum_k exp2(s_hi) ----------------
    for (int kt = 0; kt < 32; ++kt) {
        __syncthreads();
        #pragma unroll
        for (int i = 0; i < 2; ++i)
            gload_lds16(kh + headoff + ((size_t)(kt * 64 + rowS[i]) << 6) + cS[i] * 8,
                        &Ksh[i * 2048 + (t & ~63) * 8]);
        __syncthreads();

        #pragma unroll
        for (int nt = 0; nt < 4; ++nt) {
            int kr = nt * 16 + ln;
            int sz0 = ((qd     ^ (kr & 7)) << 3);
            int sz1 = (((qd + 4) ^ (kr & 7)) << 3);
            short8 b0h = *(const short8*)&Ksh[kr * 64 + sz0];
            short8 b1h = *(const short8*)&Ksh[kr * 64 + sz1];
            #pragma unroll
            for (int s = 0; s < 2; ++s) {
                f32x4 zz = (f32x4){0.f, 0.f, 0.f, 0.f};
                zz = __builtin_amdgcn_mfma_f32_16x16x32_bf16(aqh[s][0], b0h, zz, 0, 0, 0);
                zz = __builtin_amdgcn_mfma_f32_16x16x32_bf16(aqh[s][1], b1h, zz, 0, 0, 0);
                #pragma unroll
                for (int r = 0; r < 4; ++r)
                    l_run[s][r] += fexp2(zz[r]);
            }
        }
    }

    #pragma unroll
    for (int off = 1; off < 16; off <<= 1)
        #pragma unroll
        for (int s = 0; s < 2; ++s)
            #pragma unroll
            for (int r = 0; r < 4; ++r)
                l_run[s][r] += __shfl_xor(l_run[s][r], off);
    float inv_l[2][4];
    #pragma unroll
    for (int s = 0; s < 2; ++s)
        #pragma unroll
        for (int r = 0; r < 4; ++r) inv_l[s][r] = 1.0f / l_run[s][r];

    // ---------------- pass 2: column sums (k split, q hi) ----------------
    for (int kt = 0; kt < 32; ++kt) {
        __syncthreads();
        #pragma unroll
        for (int i = 0; i < 2; ++i) {
            gload_lds16(kh + headoff + ((size_t)(kt * 64 + rowS[i]) << 6) + cS[i] * 8,
                        &Ksh[i * 2048 + (t & ~63) * 8]);
            gload_lds16(kl + headoff + ((size_t)(kt * 64 + rowS[i]) << 6) + cS[i] * 8,
                        &Ksl[i * 2048 + (t & ~63) * 8]);
        }
        __syncthreads();

        float colp[4];
        #pragma unroll
        for (int nt = 0; nt < 4; ++nt) {
            int kr = nt * 16 + ln;
            int sz0 = ((qd     ^ (kr & 7)) << 3);
            int sz1 = (((qd + 4) ^ (kr & 7)) << 3);
            short8 b0h = *(const short8*)&Ksh[kr * 64 + sz0];
            short8 b1h = *(const short8*)&Ksh[kr * 64 + sz1];
            short8 b0l = *(const short8*)&Ksl[kr * 64 + sz0];
            short8 b1l = *(const short8*)&Ksl[kr * 64 + sz1];
            float cp = 0.f;
            #pragma unroll
            for (int s = 0; s < 2; ++s) {
                f32x4 zz = (f32x4){0.f, 0.f, 0.f, 0.f};
                zz = __builtin_amdgcn_mfma_f32_16x16x32_bf16(aqh[s][0], b0l, zz, 0, 0, 0);
                zz = __builtin_amdgcn_mfma_f32_16x16x32_bf16(aqh[s][1], b1l, zz, 0, 0, 0);
                zz = __builtin_amdgcn_mfma_f32_16x16x32_bf16(aqh[s][0], b0h, zz, 0, 0, 0);
                zz = __builtin_amdgcn_mfma_f32_16x16x32_bf16(aqh[s][1], b1h, zz, 0, 0, 0);
                cp += fexp2(zz[0]) * inv_l[s][0] + fexp2(zz[1]) * inv_l[s][1]
                    + fexp2(zz[2]) * inv_l[s][2] + fexp2(zz[3]) * inv_l[s][3];
            }
            colp[nt] = cp;
        }
        #pragma unroll
        for (int nt = 0; nt < 4; ++nt) {
            colp[nt] += __shfl_xor(colp[nt], 16);
            colp[nt] += __shfl_xor(colp[nt], 32);
        }
        float mine = (qd == 0) ? colp[0] : (qd == 1) ? colp[1] : (qd == 2) ? colp[2] : colp[3];
        cs_all[w][lane] = mine;
        __syncthreads();
        if (t < 64) {
            float tot = cs_all[0][t] + cs_all[1][t] + cs_all[2][t] + cs_all[3][t];
            atomicAdd(&cs[(size_t)bh * L_ + kt * 64 + t], tot);
        }
    }
}

// ---------------------------------------------------------------------------
// T[b,h,h'] = sum_l cs[b,h,l] * x[b,l,h']   (fp32, atomic over 8 l-splits)
// ---------------------------------------------------------------------------
__global__ __launch_bounds__(256) void ctx1_kernel(
    const float* __restrict__ cs, const float* __restrict__ x, float* __restrict__ T)
{
    const int o0 = blockIdx.x * 64, b = blockIdx.y, l0 = blockIdx.z * 256;
    const int t = threadIdx.x, o = t & 63, hg = t >> 6;
    __shared__ float cs_s[16][128];
    float acc[4] = {};

    for (int ch = 0; ch < 2; ++ch) {
        int lbase = l0 + ch * 128;
        __syncthreads();
        for (int i = t; i < 2048; i += 256) {
            int h = i >> 7, lc = i & 127;
            cs_s[h][lc] = cs[((size_t)(b * NH_ + h) << 11) + lbase + lc];
        }
        __syncthreads();
        for (int lc = 0; lc < 128; ++lc) {
            float xv = x[((size_t)(b * L_ + lbase + lc) << 10) + o0 + o];
            #pragma unroll
            for (int j = 0; j < 4; ++j) acc[j] += cs_s[hg * 4 + j][lc] * xv;
        }
    }
    #pragma unroll
    for (int j = 0; j < 4; ++j)
        atomicAdd(&T[((size_t)(b * NH_ + hg * 4 + j) << 10) + o0 + o], acc[j]);
}

// ---------------------------------------------------------------------------
// ctx[b,o] = sum_h' T[b, o>>6, h'] * Wv[o,h'] + L*bv[o]; wave per row
// ---------------------------------------------------------------------------
__global__ __launch_bounds__(256) void ctx2_kernel(
    const float* __restrict__ T, const float* __restrict__ Wv,
    const float* __restrict__ bv, float* __restrict__ ctx)
{
    const int gid  = blockIdx.x * 4 + (threadIdx.x >> 6);   // 0..4095
    const int lane = threadIdx.x & 63;
    const int b = gid >> 10, o = gid & (H_ - 1);
    const float4* wr = (const float4*)(Wv + (size_t)o * H_);
    const float4* tr = (const float4*)(T + ((size_t)(b * NH_ + (o >> 6)) << 10));
    float acc = 0.f;
    #pragma unroll
    for (int i = 0; i < 4; ++i) {
        float4 wv = wr[lane + i * 64];
        float4 tv = tr[lane + i * 64];
        acc += wv.x * tv.x + wv.y * tv.y + wv.z * tv.z + wv.w * tv.w;
    }
    #pragma unroll
    for (int off = 32; off; off >>= 1) acc += __shfl_xor(acc, off);
    if (lane == 0) ctx[(b << 10) + o] = acc + (float)L_ * bv[o];
}

// ---------------------------------------------------------------------------
// pooled[b,o] = bo[o] + (1/L) * sum_h ctx[b,h] * Wo[o,h]; wave per row
// ---------------------------------------------------------------------------
__global__ __launch_bounds__(256) void pooled_kernel(
    const float* __restrict__ ctx, const float* __restrict__ Wo,
    const float* __restrict__ bo, float* __restrict__ out)
{
    const int gid  = blockIdx.x * 4 + (threadIdx.x >> 6);   // 0..4095
    const int lane = threadIdx.x & 63;
    const int b = gid >> 10, o = gid & (H_ - 1);
    const float4* wr = (const float4*)(Wo + (size_t)o * H_);
    const float4* cr = (const float4*)(ctx + ((size_t)b << 10));
    float acc = 0.f;
    #pragma unroll
    for (int i = 0; i < 4; ++i) {
        float4 wv = wr[lane + i * 64];
        float4 cv = cr[lane + i * 64];
        acc += wv.x * cv.x + wv.y * cv.y + wv.z * cv.z + wv.w * cv.w;
    }
    #pragma unroll
    for (int off = 32; off; off >>= 1) acc += __shfl_xor(acc, off);
    if (lane == 0) out[(b << 10) + o] = acc * (1.0f / (float)L_) + bo[o];
}

__global__ void weights_kernel(const float* __restrict__ cs, float* __restrict__ out)
{
    int i = blockIdx.x * 256 + threadIdx.x;   // 8192
    int b = i >> 11, k = i & (L_ - 1);
    float s = 0.f;
    #pragma unroll
    for (int h = 0; h < NH_; ++h) s += cs[((size_t)(b * NH_ + h) << 11) + k];
    out[B_ * H_ + i] = s * (1.0f / (float)(NH_ * L_));
}

// ---------------------------------------------------------------------------
extern "C" void kernel_launch(void* const* d_in, const int* in_sizes, int n_in,
                              void* d_out, int out_size, void* d_ws, size_t ws_size,
                              hipStream_t stream)
{
    const float* x  = (const float*)d_in[0];
    const float* Wq = (const float*)d_in[1];
    const float* bq = (const float*)d_in[2];
    const float* Wk = (const float*)d_in[3];
    const float* bk = (const float*)d_in[4];
    const float* Wv = (const float*)d_in[5];
    const float* bv = (const float*)d_in[6];
    const float* Wo = (const float*)d_in[7];
    const float* bo = (const float*)d_in[8];
    float* out = (float*)d_out;

    float* ws  = (float*)d_ws;
    float* cs  = ws;                       // B*NH*L = 131072 f
    float* T   = ws + 131072;              // B*NH*H =  65536 f
    float* ctx = ws + 196608;              // B*H    =   4096 f
    ushort_t* base = (ushort_t*)(ws + 200704);
    const size_t QE = 8388608;             // B*NH*L*DK == B*L*H
    ushort_t* qhb = base;
    ushort_t* khb = base + QE;
    ushort_t* klb = base + 2 * QE;
    ushort_t* xhb = base + 3 * QE;
    ushort_t* xlb = base + 4 * QE;
    ushort_t* wqh = base + 5 * QE;
    ushort_t* wql = wqh + 1048576;         // scratch (unused by proj)
    ushort_t* wkh = wql + 1048576;
    ushort_t* wkl = wkh + 1048576;

    hipMemsetAsync(ws, 0, (131072 + 65536) * sizeof(float), stream);

    fsplit_kernel<<<8192, 256, 0, stream>>>(x,  xhb, xlb, 2097152);
    fsplit_kernel<<<1024, 256, 0, stream>>>(Wq, wqh, wql, 262144);
    fsplit_kernel<<<1024, 256, 0, stream>>>(Wk, wkh, wkl, 262144);

    proj_split<<<dim3(8, 64, 2), 256, 0, stream>>>(xhb, xlb, wqh, wkh, wkl,
                                                   bq, bk, qhb, khb, klb);

    attn_split<<<B_ * NH_ * (L_ / 128), 256, 0, stream>>>(qhb, khb, klb, cs);

    ctx1_kernel<<<dim3(16, 4, 8), 256, 0, stream>>>(cs, x, T);
    ctx2_kernel<<<1024, 256, 0, stream>>>(T, Wv, bv, ctx);
    pooled_kernel<<<1024, 256, 0, stream>>>(ctx, Wo, bo, out);
    weights_kernel<<<(B_ * L_) / 256, 256, 0, stream>>>(cs, out);
}